// Round 3
// baseline (2120.705 us; speedup 1.0000x reference)
//
#include <hip/hip_runtime.h>
#include <hip/hip_bf16.h>

#define Bg 32
#define Nn 512
#define Fdim 6
#define Wd 128
#define KG 100
#define KP 3
#define DIM2 1536
#define GCHUNK 8

typedef __hip_bfloat16 bf16;

__device__ __forceinline__ float b2f(bf16 v) { return __bfloat162float(v); }
__device__ __forceinline__ float lrelu(float v) { return v > 0.0f ? v : 0.01f * v; }

// ---------- dtype detection: is the float data f32 (1) or bf16 (0)? ----------
// Little-endian f32 read as u16: EVEN indices are low mantissa halves (random
// bits, ~45% have "exponent" field >= 140). Genuine bf16 N(0,1): never.
__global__ void detect_kernel(const unsigned short* __restrict__ x, int* __restrict__ flag) {
  if (threadIdx.x == 0 && blockIdx.x == 0) {
    int big = 0;
    for (int i = 0; i < 512; i += 2) {
      unsigned short u = x[i];
      int e = (u >> 7) & 0xFF;
      if (e >= 140) big++;
    }
    *flag = (big > 20) ? 1 : 0;
  }
}

// ---------- convert x (bf16 or f32) -> f32 ----------
__global__ void convert_kernel(const void* __restrict__ x, float* __restrict__ xf, int n,
                               const int* __restrict__ flag) {
  int i = blockIdx.x * 256 + threadIdx.x;
  if (i >= n) return;
  if (*flag) xf[i] = ((const float*)x)[i];
  else       xf[i] = b2f(((const bf16*)x)[i]);
}

// ---------- bitonic sort of 512 u64 keys with 256 threads ----------
__device__ void bitonic512(unsigned long long* key, int t) {
  for (int k = 2; k <= 512; k <<= 1) {
    for (int j = k >> 1; j > 0; j >>= 1) {
      __syncthreads();
      #pragma unroll
      for (int ee = 0; ee < 2; ee++) {
        int e = t + ee * 256;
        int p = e ^ j;
        if (p > e) {
          unsigned long long a = key[e], b = key[p];
          bool up = ((e & k) == 0);
          if ((a > b) == up) { key[e] = b; key[p] = a; }
        }
      }
    }
  }
  __syncthreads();
}

// ---------- kNN on 6-d coords ----------
__global__ void knn_x_kernel(const float* __restrict__ xf, int* __restrict__ nbr, int kout) {
  __shared__ float xg[Nn * Fdim];
  __shared__ unsigned long long key[Nn];
  int row = blockIdx.x; int g = row >> 9; int i = row & 511; int t = threadIdx.x;
  const float* xp = xf + g * (Nn * Fdim);
  for (int idx = t; idx < Nn * Fdim; idx += 256) xg[idx] = xp[idx];
  __syncthreads();
  float xi[Fdim];
  #pragma unroll
  for (int c = 0; c < Fdim; c++) xi[c] = xg[i * Fdim + c];
  float sqi = 0.0f;
  #pragma unroll
  for (int c = 0; c < Fdim; c++) sqi += xi[c] * xi[c];
  for (int e = t; e < Nn; e += 256) {
    float dot = 0.0f, sqj = 0.0f;
    #pragma unroll
    for (int c = 0; c < Fdim; c++) { float v = xg[e * Fdim + c]; dot += xi[c] * v; sqj += v * v; }
    float d = sqi + sqj - 2.0f * dot;
    if (e == i) d += 1e10f;
    unsigned u = __float_as_uint(d);
    u = (u & 0x80000000u) ? ~u : (u | 0x80000000u);
    key[e] = ((unsigned long long)u << 32) | (unsigned)e;
  }
  bitonic512(key, t);
  for (int e = t; e < kout; e += 256) nbr[row * kout + e] = (int)(key[e] & 0xFFFFFFFFu);
}

// ---------- kNN from (chunked) Gram matrix + squared norms ----------
__global__ void knn_gram_kernel(const float* __restrict__ G, const float* __restrict__ sqn,
                                int* __restrict__ nbr, int kout, int g0) {
  __shared__ float sq[Nn];
  __shared__ unsigned long long key[Nn];
  int bid = blockIdx.x;             // 0 .. GCHUNK*512-1
  int gl = bid >> 9; int i = bid & 511; int t = threadIdx.x;
  int g = g0 + gl; int row = g * Nn + i;
  const float* sp = sqn + g * Nn;
  for (int e = t; e < Nn; e += 256) sq[e] = sp[e];
  __syncthreads();
  float sqi = sq[i];
  const float* Gr = G + ((size_t)gl * Nn + i) * Nn;
  for (int e = t; e < Nn; e += 256) {
    float d = sqi + sq[e] - 2.0f * Gr[e];
    if (e == i) d += 1e10f;
    unsigned u = __float_as_uint(d);
    u = (u & 0x80000000u) ? ~u : (u | 0x80000000u);
    key[e] = ((unsigned long long)u << 32) | (unsigned)e;
  }
  bitonic512(key, t);
  for (int e = t; e < kout; e += 256) nbr[row * kout + e] = (int)(key[e] & 0xFFFFFFFFu);
}

// ---------- neighbor-mean over 100, C=6 ----------
__global__ void gm6_kernel(const float* __restrict__ src, const int* __restrict__ nbr,
                           float* __restrict__ dst) {
  __shared__ float s[Nn * Fdim];
  int g = blockIdx.x; int t = threadIdx.x;  // 512
  const float* sp = src + g * (Nn * Fdim);
  for (int idx = t; idx < Nn * Fdim; idx += 512) s[idx] = sp[idx];
  __syncthreads();
  float acc[Fdim] = {0, 0, 0, 0, 0, 0};
  const int* nb = nbr + ((size_t)(g * Nn + t)) * KG;
  for (int k = 0; k < KG; k++) {
    int j = nb[k];
    #pragma unroll
    for (int c = 0; c < Fdim; c++) acc[c] += s[j * Fdim + c];
  }
  float* dp = dst + (size_t)(g * Nn + t) * Fdim;
  #pragma unroll
  for (int c = 0; c < Fdim; c++) dp[c] = acc[c] / 100.0f;
}

// ---------- neighbor-mean over 100, C=128 ----------
__global__ void gm128_kernel(const float* __restrict__ src, const int* __restrict__ nbr,
                             float* __restrict__ dst) {
  __shared__ int ids[KG];
  int row = blockIdx.x; int g = row >> 9; int t = threadIdx.x;  // 128
  if (t < KG) ids[t] = nbr[(size_t)row * KG + t];
  __syncthreads();
  const float* sp = src + (size_t)g * Nn * Wd;
  float acc = 0.0f;
  #pragma unroll 4
  for (int k = 0; k < KG; k++) acc += sp[ids[k] * Wd + t];
  dst[(size_t)row * Wd + t] = acc / 100.0f;
}

// ---------- out = lrelu(in0@W[0] + in1@W[1] + in2@W[2] + b) ----------
__global__ void proj3_kernel(const float* __restrict__ in0, const float* __restrict__ in1,
                             const float* __restrict__ in2, const void* __restrict__ Wt_,
                             const void* __restrict__ bt_, float* __restrict__ out, int C,
                             long Woff, long boff, const int* __restrict__ flag) {
  __shared__ float s0[8 * 128], s1[8 * 128], s2[8 * 128];
  int t = threadIdx.x;  // 128
  int node0 = blockIdx.x * 8;
  int f32 = *flag;
  int nC = 8 * C;
  for (int idx = t; idx < nC; idx += 128) {
    s0[idx] = in0[(size_t)node0 * C + idx];
    s1[idx] = in1[(size_t)node0 * C + idx];
    s2[idx] = in2[(size_t)node0 * C + idx];
  }
  __syncthreads();
  float acc[8] = {0, 0, 0, 0, 0, 0, 0, 0};
  float bd;
  if (f32) {
    const float* W = (const float*)Wt_ + Woff;
    for (int c = 0; c < C; c++) {
      float w0 = W[c * 128 + t], w1 = W[(C + c) * 128 + t], w2 = W[(2 * C + c) * 128 + t];
      #pragma unroll
      for (int n = 0; n < 8; n++)
        acc[n] += s0[n * C + c] * w0 + s1[n * C + c] * w1 + s2[n * C + c] * w2;
    }
    bd = ((const float*)bt_ + boff)[t];
  } else {
    const bf16* W = (const bf16*)Wt_ + Woff;
    for (int c = 0; c < C; c++) {
      float w0 = b2f(W[c * 128 + t]), w1 = b2f(W[(C + c) * 128 + t]), w2 = b2f(W[(2 * C + c) * 128 + t]);
      #pragma unroll
      for (int n = 0; n < 8; n++)
        acc[n] += s0[n * C + c] * w0 + s1[n * C + c] * w1 + s2[n * C + c] * w2;
    }
    bd = b2f(((const bf16*)bt_ + boff)[t]);
  }
  #pragma unroll
  for (int n = 0; n < 8; n++)
    out[(size_t)(node0 + n) * 128 + t] = lrelu(acc[n] + bd);
}

// ---------- u = in@W[0:C], v = in@W[C:2C] ----------
__global__ void proj_dual_kernel(const float* __restrict__ in, const void* __restrict__ Wt_,
                                 float* __restrict__ u, float* __restrict__ v, int C,
                                 long Woff, const int* __restrict__ flag) {
  __shared__ float s0[8 * 128];
  int t = threadIdx.x; int node0 = blockIdx.x * 8;
  int f32 = *flag;
  for (int idx = t; idx < 8 * C; idx += 128) s0[idx] = in[(size_t)node0 * C + idx];
  __syncthreads();
  float au[8] = {0, 0, 0, 0, 0, 0, 0, 0};
  float av[8] = {0, 0, 0, 0, 0, 0, 0, 0};
  if (f32) {
    const float* W = (const float*)Wt_ + Woff;
    for (int c = 0; c < C; c++) {
      float wa = W[c * 128 + t], wb = W[(C + c) * 128 + t];
      #pragma unroll
      for (int n = 0; n < 8; n++) { float x = s0[n * C + c]; au[n] += x * wa; av[n] += x * wb; }
    }
  } else {
    const bf16* W = (const bf16*)Wt_ + Woff;
    for (int c = 0; c < C; c++) {
      float wa = b2f(W[c * 128 + t]), wb = b2f(W[(C + c) * 128 + t]);
      #pragma unroll
      for (int n = 0; n < 8; n++) { float x = s0[n * C + c]; au[n] += x * wa; av[n] += x * wb; }
    }
  }
  #pragma unroll
  for (int n = 0; n < 8; n++) {
    u[(size_t)(node0 + n) * 128 + t] = au[n];
    v[(size_t)(node0 + n) * 128 + t] = av[n];
  }
}

// ---------- edgeconv1 ----------
__global__ void edge_mlp1_kernel(const float* __restrict__ u, const float* __restrict__ v,
                                 const int* __restrict__ nbrp, const void* __restrict__ W2_,
                                 const void* __restrict__ b1_, const void* __restrict__ b2_,
                                 float* __restrict__ y, const int* __restrict__ flag) {
  __shared__ float tl[8][3][128];
  int t = threadIdx.x; int node0 = blockIdx.x * 8; int g = node0 >> 9;
  int f32 = *flag;
  float b1d;
  if (f32) b1d = ((const float*)b1_)[t]; else b1d = b2f(((const bf16*)b1_)[t]);
  for (int n = 0; n < 8; n++) {
    int row = node0 + n;
    float ui = u[(size_t)row * 128 + t], vi = v[(size_t)row * 128 + t];
    #pragma unroll
    for (int k = 0; k < 3; k++) {
      int j = nbrp[row * 3 + k];
      tl[n][k][t] = lrelu(ui + v[(size_t)(g * Nn + j) * 128 + t] - vi + b1d);
    }
  }
  __syncthreads();
  float acc[8][3];
  #pragma unroll
  for (int n = 0; n < 8; n++)
    #pragma unroll
    for (int k = 0; k < 3; k++) acc[n][k] = 0.0f;
  if (f32) {
    const float* W = (const float*)W2_;
    for (int c = 0; c < 128; c++) {
      float w = W[c * 128 + t];
      #pragma unroll
      for (int n = 0; n < 8; n++)
        #pragma unroll
        for (int k = 0; k < 3; k++) acc[n][k] += tl[n][k][c] * w;
    }
  } else {
    const bf16* W = (const bf16*)W2_;
    for (int c = 0; c < 128; c++) {
      float w = b2f(W[c * 128 + t]);
      #pragma unroll
      for (int n = 0; n < 8; n++)
        #pragma unroll
        for (int k = 0; k < 3; k++) acc[n][k] += tl[n][k][c] * w;
    }
  }
  float b2d;
  if (f32) b2d = ((const float*)b2_)[t]; else b2d = b2f(((const bf16*)b2_)[t]);
  #pragma unroll
  for (int n = 0; n < 8; n++) {
    float m = lrelu(acc[n][0] + b2d);
    m = fmaxf(m, lrelu(acc[n][1] + b2d));
    m = fmaxf(m, lrelu(acc[n][2] + b2d));
    y[(size_t)(node0 + n) * 128 + t] = m;
  }
}

// ---------- edgeconv2/3 ----------
__global__ void edge_max_kernel(const float* __restrict__ u, const float* __restrict__ v,
                                const int* __restrict__ nbrp, const void* __restrict__ bias_,
                                float* __restrict__ y, long boff, const int* __restrict__ flag) {
  int row = blockIdx.x; int g = row >> 9; int t = threadIdx.x;  // 128
  float ui = u[(size_t)row * 128 + t], vi = v[(size_t)row * 128 + t];
  float bd;
  if (*flag) bd = ((const float*)bias_ + boff)[t]; else bd = b2f(((const bf16*)bias_ + boff)[t]);
  float m = -3.4e38f;
  #pragma unroll
  for (int k = 0; k < 3; k++) {
    int j = nbrp[row * 3 + k];
    m = fmaxf(m, lrelu(ui - vi + v[(size_t)(g * Nn + j) * 128 + t] + bd));
  }
  y[(size_t)row * 128 + t] = m;
}

// ---------- squared norms ----------
__global__ void sqn_kernel(const float* __restrict__ y, float* __restrict__ sqn) {
  int row = blockIdx.x; int t = threadIdx.x;  // 64
  float a = y[(size_t)row * 128 + t], b = y[(size_t)row * 128 + t + 64];
  float s = a * a + b * b;
  #pragma unroll
  for (int off = 32; off > 0; off >>= 1) s += __shfl_down(s, off);
  if (t == 0) sqn[row] = s;
}

// ---------- chunked Gram matrix: G[gl] = Y[g0+gl] Y[g0+gl]^T ----------
__global__ void gram_kernel(const float* __restrict__ y, float* __restrict__ G, int g0) {
  __shared__ float As[64][17], Bs[64][17];
  int bid = blockIdx.x;             // 0 .. GCHUNK*64-1
  int gl = bid >> 6; int tt = bid & 63; int ti = tt >> 3; int tj = tt & 7;
  int g = g0 + gl;
  int t = threadIdx.x; int tx = t & 15, ty = t >> 4;
  const float* Yg = y + (size_t)g * Nn * Wd;
  float* Gg = G + (size_t)gl * Nn * Nn;
  float c[4][4];
  #pragma unroll
  for (int p = 0; p < 4; p++)
    #pragma unroll
    for (int q = 0; q < 4; q++) c[p][q] = 0.0f;
  for (int k0 = 0; k0 < 128; k0 += 16) {
    for (int idx = t; idx < 1024; idx += 256) {
      int r = idx >> 4, cc = idx & 15;
      As[r][cc] = Yg[(ti * 64 + r) * 128 + k0 + cc];
      Bs[r][cc] = Yg[(tj * 64 + r) * 128 + k0 + cc];
    }
    __syncthreads();
    for (int kk = 0; kk < 16; kk++) {
      float a[4], bb[4];
      #pragma unroll
      for (int p = 0; p < 4; p++) a[p] = As[ty * 4 + p][kk];
      #pragma unroll
      for (int q = 0; q < 4; q++) bb[q] = Bs[tx * 4 + q][kk];
      #pragma unroll
      for (int p = 0; p < 4; p++)
        #pragma unroll
        for (int q = 0; q < 4; q++) c[p][q] += a[p] * bb[q];
    }
    __syncthreads();
  }
  #pragma unroll
  for (int p = 0; p < 4; p++)
    #pragma unroll
    for (int q = 0; q < 4; q++)
      Gg[(size_t)(ti * 64 + ty * 4 + p) * Nn + tj * 64 + tx * 4 + q] = c[p][q];
}

// ---------- mean+max pool ----------
__global__ void pool_kernel(const float* __restrict__ h, float* __restrict__ z,
                            int meanoff, int maxoff) {
  __shared__ float sm[4][128], sx[4][128];
  int g = blockIdx.x; int t = threadIdx.x;  // 512
  int c = t & 127, q = t >> 7;
  const float* hg = h + (size_t)g * Nn * Wd;
  float s = 0.0f, m = -3.4e38f;
  for (int n = q * 128; n < q * 128 + 128; n++) {
    float vv = hg[n * 128 + c];
    s += vv; m = fmaxf(m, vv);
  }
  sm[q][c] = s; sx[q][c] = m;
  __syncthreads();
  if (q == 0) {
    s = sm[0][c] + sm[1][c] + sm[2][c] + sm[3][c];
    m = fmaxf(fmaxf(sx[0][c], sx[1][c]), fmaxf(sx[2][c], sx[3][c]));
    z[g * DIM2 + meanoff + c] = s / 512.0f;
    z[g * DIM2 + maxoff + c] = m;
  }
}

// ---------- BatchNorm1d (batch stats), in place ----------
__global__ void bn_kernel(float* __restrict__ z, const void* __restrict__ gamma,
                          const void* __restrict__ beta, const int* __restrict__ flag) {
  int c = blockIdx.x * 256 + threadIdx.x;
  if (c >= DIM2) return;
  float s = 0.0f;
  for (int r = 0; r < Bg; r++) s += z[r * DIM2 + c];
  float mu = s / 32.0f;
  float v = 0.0f;
  for (int r = 0; r < Bg; r++) { float d = z[r * DIM2 + c] - mu; v += d * d; }
  float var = v / 32.0f;
  float gm, bt;
  if (*flag) { gm = ((const float*)gamma)[c]; bt = ((const float*)beta)[c]; }
  else       { gm = b2f(((const bf16*)gamma)[c]); bt = b2f(((const bf16*)beta)[c]); }
  float scale = gm / sqrtf(var + 1e-5f);
  for (int r = 0; r < Bg; r++) z[r * DIM2 + c] = (z[r * DIM2 + c] - mu) * scale + bt;
}

// ---------- head linear ----------
__global__ void hl_kernel(const float* __restrict__ in, const void* __restrict__ Wt_,
                          const void* __restrict__ bt_, float* __restrict__ out,
                          long Woff, long boff, const int* __restrict__ flag) {
  __shared__ float a[32 * 129];
  int t = threadIdx.x; int dcol = blockIdx.x * 8 + (t >> 5); int r = t & 31;
  int f32 = *flag;
  float acc = 0.0f;
  for (int k0 = 0; k0 < DIM2; k0 += 128) {
    for (int idx = t; idx < 4096; idx += 256) {
      int rr = idx >> 7, kk = idx & 127;
      a[rr * 129 + kk] = in[rr * DIM2 + k0 + kk];
    }
    __syncthreads();
    if (f32) {
      const float* W = (const float*)Wt_ + Woff;
      for (int kk = 0; kk < 128; kk++)
        acc += a[r * 129 + kk] * W[(size_t)(k0 + kk) * DIM2 + dcol];
    } else {
      const bf16* W = (const bf16*)Wt_ + Woff;
      for (int kk = 0; kk < 128; kk++)
        acc += a[r * 129 + kk] * b2f(W[(size_t)(k0 + kk) * DIM2 + dcol]);
    }
    __syncthreads();
  }
  float bd;
  if (f32) bd = ((const float*)bt_ + boff)[dcol]; else bd = b2f(((const bf16*)bt_ + boff)[dcol]);
  out[r * DIM2 + dcol] = lrelu(acc + bd);
}

// ---------- final ----------
__global__ void final_kernel(const float* __restrict__ zin, const void* __restrict__ outW,
                             const void* __restrict__ outb, void* __restrict__ out,
                             const int* __restrict__ flag) {
  __shared__ float red[256];
  int r = blockIdx.x, t = threadIdx.x;
  int f32 = *flag;
  float acc = 0.0f;
  if (f32) {
    const float* W = (const float*)outW;
    for (int c = t; c < DIM2; c += 256) acc += zin[r * DIM2 + c] * W[c];
  } else {
    const bf16* W = (const bf16*)outW;
    for (int c = t; c < DIM2; c += 256) acc += zin[r * DIM2 + c] * b2f(W[c]);
  }
  red[t] = acc; __syncthreads();
  for (int s = 128; s > 0; s >>= 1) { if (t < s) red[t] += red[t + s]; __syncthreads(); }
  if (t == 0) {
    float ob;
    if (f32) ob = ((const float*)outb)[0]; else ob = b2f(((const bf16*)outb)[0]);
    float val = red[0] + ob;
    if (f32) ((float*)out)[r] = val;
    else     ((bf16*)out)[r] = __float2bfloat16(val);
  }
}

extern "C" void kernel_launch(void* const* d_in, const int* in_sizes, int n_in,
                              void* d_out, int out_size, void* d_ws, size_t ws_size,
                              hipStream_t stream) {
  const void* x      = d_in[0];
  const void* tag1_W = d_in[2];
  const void* tag1_b = d_in[3];
  const void* tag_W  = d_in[4];
  const void* tag_b  = d_in[5];
  const void* p1_W1  = d_in[6];
  const void* p1_b1  = d_in[7];
  const void* p1_W2  = d_in[8];
  const void* p1_b2  = d_in[9];
  const void* pf_W   = d_in[10];
  const void* pf_b   = d_in[11];
  const void* bn_g   = d_in[12];
  const void* bn_b   = d_in[13];
  const void* lin_W  = d_in[14];
  const void* lin_b  = d_in[15];
  const void* out_W  = d_in[16];
  const void* out_b  = d_in[17];

  // ---- workspace layout: total 10,485,776 floats ≈ 40 MB ----
  float* ws = (float*)d_ws;
  float* XF   = ws + 0;                 // 98304
  float* M16  = ws + 98304;             // 98304
  float* M26  = ws + 196608;            // 98304
  float* Z    = ws + 294912;            // 49152
  float* ZB   = ws + 344064;            // 49152
  float* SQ   = ws + 393216;            // 16384
  int*   FLAG = (int*)(ws + 409600);    // 16
  int*   NBRP = (int*)(ws + 409616);    // 49152 ints
  int*   NBRG = (int*)(ws + 458768);    // 1,638,400 ints -> ends 2,097,168
  float* S0   = ws + 2097168;           // 4 slots x 2,097,152 floats (8 MB each)
  float* S1   = ws + 4194320;
  float* S2   = ws + 6291472;
  float* S3   = ws + 8388624;           // ends 10,485,776 floats

  detect_kernel<<<1, 64, 0, stream>>>((const unsigned short*)x, FLAG);
  convert_kernel<<<384, 256, 0, stream>>>(x, XF, Bg * Nn * Fdim, FLAG);
  knn_x_kernel<<<Bg * Nn, 256, 0, stream>>>(XF, NBRG, KG);
  knn_x_kernel<<<Bg * Nn, 256, 0, stream>>>(XF, NBRP, KP);

  // ---- TAG branch: Hb=S0, M1=S1, M2=S2, HN=S3 ----
  gm6_kernel<<<Bg, 512, 0, stream>>>(XF, NBRG, M16);
  gm6_kernel<<<Bg, 512, 0, stream>>>(M16, NBRG, M26);
  proj3_kernel<<<2048, 128, 0, stream>>>(XF, M16, M26, tag1_W, tag1_b, S0, 6, 0, 0, FLAG);
  pool_kernel<<<Bg, 512, 0, stream>>>(S0, Z, 0, 128);

  gm128_kernel<<<Bg * Nn, 128, 0, stream>>>(S0, NBRG, S1);
  gm128_kernel<<<Bg * Nn, 128, 0, stream>>>(S1, NBRG, S2);
  proj3_kernel<<<2048, 128, 0, stream>>>(S0, S1, S2, tag_W, tag_b, S3, 128, 0, 0, FLAG);
  pool_kernel<<<Bg, 512, 0, stream>>>(S3, Z, 256, 384);

  gm128_kernel<<<Bg * Nn, 128, 0, stream>>>(S3, NBRG, S1);
  gm128_kernel<<<Bg * Nn, 128, 0, stream>>>(S1, NBRG, S2);
  proj3_kernel<<<2048, 128, 0, stream>>>(S3, S1, S2, tag_W, tag_b, S0, 128,
                                         3L * 128 * 128, 128, FLAG);
  pool_kernel<<<Bg, 512, 0, stream>>>(S0, Z, 512, 640);

  // ---- point branch: U=S0, V=S1 reused; Y/G rotate through S2/S3 ----
  proj_dual_kernel<<<2048, 128, 0, stream>>>(XF, p1_W1, S0, S1, 6, 0, FLAG);
  edge_mlp1_kernel<<<2048, 128, 0, stream>>>(S0, S1, NBRP, p1_W2, p1_b1, p1_b2, S2, FLAG);  // Y0=S2
  pool_kernel<<<Bg, 512, 0, stream>>>(S2, Z, 768, 1152);

  sqn_kernel<<<Bg * Nn, 64, 0, stream>>>(S2, SQ);
  for (int c = 0; c < Bg; c += GCHUNK) {           // G=S3 (chunked)
    gram_kernel<<<GCHUNK * 64, 256, 0, stream>>>(S2, S3, c);
    knn_gram_kernel<<<GCHUNK * Nn, 256, 0, stream>>>(S3, SQ, NBRP, KP, c);
  }
  proj_dual_kernel<<<2048, 128, 0, stream>>>(S2, pf_W, S0, S1, 128, 0, FLAG);  // Y0 dead
  edge_max_kernel<<<Bg * Nn, 128, 0, stream>>>(S0, S1, NBRP, pf_b, S3, 0, FLAG);  // Y1=S3 (G dead)
  pool_kernel<<<Bg, 512, 0, stream>>>(S3, Z, 896, 1280);

  sqn_kernel<<<Bg * Nn, 64, 0, stream>>>(S3, SQ);
  for (int c = 0; c < Bg; c += GCHUNK) {           // G=S2 (Y0 dead)
    gram_kernel<<<GCHUNK * 64, 256, 0, stream>>>(S3, S2, c);
    knn_gram_kernel<<<GCHUNK * Nn, 256, 0, stream>>>(S2, SQ, NBRP, KP, c);
  }
  proj_dual_kernel<<<2048, 128, 0, stream>>>(S3, pf_W, S0, S1, 128, 256L * 128, FLAG);  // Y1 dead
  edge_max_kernel<<<Bg * Nn, 128, 0, stream>>>(S0, S1, NBRP, pf_b, S2, 128, FLAG);  // Y2=S2
  pool_kernel<<<Bg, 512, 0, stream>>>(S2, Z, 1024, 1408);

  // ---- head ----
  bn_kernel<<<6, 256, 0, stream>>>(Z, bn_g, bn_b, FLAG);
  hl_kernel<<<192, 256, 0, stream>>>(Z, lin_W, lin_b, ZB, 0L, 0L, FLAG);
  hl_kernel<<<192, 256, 0, stream>>>(ZB, lin_W, lin_b, Z, 1L * DIM2 * DIM2, 1L * DIM2, FLAG);
  hl_kernel<<<192, 256, 0, stream>>>(Z, lin_W, lin_b, ZB, 2L * DIM2 * DIM2, 2L * DIM2, FLAG);
  hl_kernel<<<192, 256, 0, stream>>>(ZB, lin_W, lin_b, Z, 3L * DIM2 * DIM2, 3L * DIM2, FLAG);
  hl_kernel<<<192, 256, 0, stream>>>(Z, lin_W, lin_b, ZB, 4L * DIM2 * DIM2, 4L * DIM2, FLAG);
  final_kernel<<<Bg, 256, 0, stream>>>(ZB, out_W, out_b, d_out, FLAG);
}

// Round 4
// 1882.828 us; speedup vs baseline: 1.1263x; 1.1263x over previous
//
#include <hip/hip_runtime.h>
#include <hip/hip_bf16.h>

#define Bg 32
#define Nn 512
#define Fdim 6
#define Wd 128
#define KG 100
#define KP 3
#define DIM2 1536
#define GC16 16

typedef __hip_bfloat16 bf16;

__device__ __forceinline__ float b2f(bf16 v) { return __bfloat162float(v); }
__device__ __forceinline__ float lrelu(float v) { return v > 0.0f ? v : 0.01f * v; }

// ---------- dtype detection (f32=1 / bf16=0), from low-half u16 bit patterns ----------
__global__ void detect_kernel(const unsigned short* __restrict__ x, int* __restrict__ flag) {
  if (threadIdx.x == 0 && blockIdx.x == 0) {
    int big = 0;
    for (int i = 0; i < 512; i += 2) {
      unsigned short u = x[i];
      int e = (u >> 7) & 0xFF;
      if (e >= 140) big++;
    }
    *flag = (big > 20) ? 1 : 0;
  }
}

// ---------- convert x -> f32 ----------
__global__ void convert_kernel(const void* __restrict__ x, float* __restrict__ xf, int n,
                               const int* __restrict__ flag) {
  int i = blockIdx.x * 256 + threadIdx.x;
  if (i >= n) return;
  if (*flag) xf[i] = ((const float*)x)[i];
  else       xf[i] = b2f(((const bf16*)x)[i]);
}

// ---------- sorted-3 insertion on u64 keys ----------
__device__ __forceinline__ void ins3(unsigned long long key, unsigned long long& k0,
                                     unsigned long long& k1, unsigned long long& k2) {
  if (key < k2) {
    if (key < k1) {
      k2 = k1;
      if (key < k0) { k1 = k0; k0 = key; } else k1 = key;
    } else k2 = key;
  }
}

// ---------- kNN k=100 via histogram radix-select (exact set, unsorted output) ----------
__global__ void knn100_kernel(const float* __restrict__ xf, int* __restrict__ nbr) {
  __shared__ float xg[Nn * Fdim];          // 12 KB
  __shared__ unsigned md[Nn];              // monotone dist bits, 2 KB
  __shared__ unsigned hist[Nn];            // 512 bins, 2 KB
  __shared__ unsigned short cand[Nn];      // boundary-bin candidates, 1 KB
  __shared__ int scal[4];                  // B, r, candCount, outSlot
  int row = blockIdx.x; int g = row >> 9; int i = row & 511; int t = threadIdx.x;
  const float* xp = xf + g * (Nn * Fdim);
  for (int idx = t; idx < Nn * Fdim; idx += 256) xg[idx] = xp[idx];
  hist[t] = 0; hist[t + 256] = 0;
  if (t < 4) scal[t] = 0;
  __syncthreads();
  float xi[Fdim];
  #pragma unroll
  for (int c = 0; c < Fdim; c++) xi[c] = xg[i * Fdim + c];
  float sqi = 0.0f;
  #pragma unroll
  for (int c = 0; c < Fdim; c++) sqi += xi[c] * xi[c];
  #pragma unroll
  for (int ee = 0; ee < 2; ee++) {
    int e = t + ee * 256;
    float dot = 0.0f, sqj = 0.0f;
    #pragma unroll
    for (int c = 0; c < Fdim; c++) { float v = xg[e * Fdim + c]; dot += xi[c] * v; sqj += v * v; }
    float d = sqi + sqj - 2.0f * dot;
    if (e == i) d += 1e10f;
    unsigned u = __float_as_uint(d);
    unsigned m = (u & 0x80000000u) ? ~u : (u | 0x80000000u);
    md[e] = m;
    atomicAdd(&hist[m >> 23], 1u);
  }
  __syncthreads();
  // inclusive scan of 512 bins (Hillis-Steele, 2 elems/thread)
  for (int off = 1; off < 512; off <<= 1) {
    int e0 = t, e1 = t + 256;
    unsigned a0 = (e0 >= off) ? hist[e0 - off] : 0u;
    unsigned a1 = hist[e1 - off];
    __syncthreads();
    hist[e0] += a0; hist[e1] += a1;
    __syncthreads();
  }
  // find boundary bin B = smallest bin with inclusive count >= 100
  #pragma unroll
  for (int ee = 0; ee < 2; ee++) {
    int e = t + ee * 256;
    unsigned inc = hist[e];
    unsigned exc = (e == 0) ? 0u : hist[e - 1];
    if (inc >= (unsigned)KG && exc < (unsigned)KG) { scal[0] = e; scal[1] = KG - (int)exc; }
  }
  __syncthreads();
  int B = scal[0], r = scal[1];
  int* outp = nbr + (size_t)row * KG;
  #pragma unroll
  for (int ee = 0; ee < 2; ee++) {
    int e = t + ee * 256;
    int bin = md[e] >> 23;
    if (bin < B) { int s = atomicAdd(&scal[3], 1); outp[s] = e; }
    else if (bin == B) { int c = atomicAdd(&scal[2], 1); cand[c] = (unsigned short)e; }
  }
  __syncthreads();
  int nc = scal[2];
  // exact rank within boundary bin (keys unique via (m, idx))
  for (int ci = t; ci < nc; ci += 256) {
    int e = cand[ci]; unsigned me = md[e];
    int rank = 0;
    for (int j = 0; j < nc; j++) {
      int ej = cand[j]; unsigned mj = md[ej];
      if (mj < me || (mj == me && ej < e)) rank++;
    }
    if (rank < r) { int s = atomicAdd(&scal[3], 1); outp[s] = e; }
  }
}

// ---------- kNN k=3 on coords: one wave per row, 4 rows/block ----------
__global__ void knn3_x_kernel(const float* __restrict__ xf, int* __restrict__ nbr) {
  __shared__ float xg[Nn * Fdim];
  int bid = blockIdx.x; int t = threadIdx.x; int w = t >> 6; int l = t & 63;
  int row0 = bid * 4; int g = row0 >> 9;
  const float* xp = xf + g * (Nn * Fdim);
  for (int idx = t; idx < Nn * Fdim; idx += 256) xg[idx] = xp[idx];
  __syncthreads();
  int i = (row0 & 511) + w;
  float xi[Fdim];
  #pragma unroll
  for (int c = 0; c < Fdim; c++) xi[c] = xg[i * Fdim + c];
  float sqi = 0.0f;
  #pragma unroll
  for (int c = 0; c < Fdim; c++) sqi += xi[c] * xi[c];
  unsigned long long k0 = ~0ull, k1 = ~0ull, k2 = ~0ull;
  #pragma unroll
  for (int ch = 0; ch < 8; ch++) {
    int j = ch * 64 + l;
    float dot = 0.0f, sqj = 0.0f;
    #pragma unroll
    for (int c = 0; c < Fdim; c++) { float v = xg[j * Fdim + c]; dot += xi[c] * v; sqj += v * v; }
    float d = sqi + sqj - 2.0f * dot;
    if (j == i) d += 1e10f;
    unsigned u = __float_as_uint(d);
    unsigned m = (u & 0x80000000u) ? ~u : (u | 0x80000000u);
    unsigned long long key = ((unsigned long long)m << 32) | (unsigned)j;
    ins3(key, k0, k1, k2);
  }
  #pragma unroll
  for (int off = 32; off >= 1; off >>= 1) {
    unsigned long long b0 = __shfl_xor(k0, off, 64);
    unsigned long long b1 = __shfl_xor(k1, off, 64);
    unsigned long long b2 = __shfl_xor(k2, off, 64);
    ins3(b0, k0, k1, k2); ins3(b1, k0, k1, k2); ins3(b2, k0, k1, k2);
  }
  if (l == 0) {
    int row = (g << 9) + i;
    nbr[row * 3 + 0] = (int)(k0 & 0xFFFFFFFFu);
    nbr[row * 3 + 1] = (int)(k1 & 0xFFFFFFFFu);
    nbr[row * 3 + 2] = (int)(k2 & 0xFFFFFFFFu);
  }
}

// ---------- kNN k=3 from chunked Gram: one wave per row, 4 rows/block ----------
__global__ void knn3_gram_kernel(const float* __restrict__ G, const float* __restrict__ sqn,
                                 int* __restrict__ nbr, int g0) {
  __shared__ float sq[Nn];
  int bid = blockIdx.x; int t = threadIdx.x; int w = t >> 6; int l = t & 63;
  int lr0 = bid * 4; int gl = lr0 >> 9; int g = g0 + gl;
  const float* sp = sqn + g * Nn;
  for (int idx = t; idx < Nn; idx += 256) sq[idx] = sp[idx];
  __syncthreads();
  int i = (lr0 & 511) + w;
  float sqi = sq[i];
  const float* Gr = G + ((size_t)(gl * Nn + i)) * Nn;
  unsigned long long k0 = ~0ull, k1 = ~0ull, k2 = ~0ull;
  #pragma unroll
  for (int ch = 0; ch < 8; ch++) {
    int j = ch * 64 + l;
    float d = sqi + sq[j] - 2.0f * Gr[j];
    if (j == i) d += 1e10f;
    unsigned u = __float_as_uint(d);
    unsigned m = (u & 0x80000000u) ? ~u : (u | 0x80000000u);
    unsigned long long key = ((unsigned long long)m << 32) | (unsigned)j;
    ins3(key, k0, k1, k2);
  }
  #pragma unroll
  for (int off = 32; off >= 1; off >>= 1) {
    unsigned long long b0 = __shfl_xor(k0, off, 64);
    unsigned long long b1 = __shfl_xor(k1, off, 64);
    unsigned long long b2 = __shfl_xor(k2, off, 64);
    ins3(b0, k0, k1, k2); ins3(b1, k0, k1, k2); ins3(b2, k0, k1, k2);
  }
  if (l == 0) {
    int row = g * Nn + i;
    nbr[row * 3 + 0] = (int)(k0 & 0xFFFFFFFFu);
    nbr[row * 3 + 1] = (int)(k1 & 0xFFFFFFFFu);
    nbr[row * 3 + 2] = (int)(k2 & 0xFFFFFFFFu);
  }
}

// ---------- neighbor-mean over 100, C=6 ----------
__global__ void gm6_kernel(const float* __restrict__ src, const int* __restrict__ nbr,
                           float* __restrict__ dst) {
  __shared__ float s[Nn * Fdim];
  int g = blockIdx.x; int t = threadIdx.x;  // 512
  const float* sp = src + g * (Nn * Fdim);
  for (int idx = t; idx < Nn * Fdim; idx += 512) s[idx] = sp[idx];
  __syncthreads();
  float acc[Fdim] = {0, 0, 0, 0, 0, 0};
  const int* nb = nbr + ((size_t)(g * Nn + t)) * KG;
  for (int k = 0; k < KG; k++) {
    int j = nb[k];
    #pragma unroll
    for (int c = 0; c < Fdim; c++) acc[c] += s[j * Fdim + c];
  }
  float* dp = dst + (size_t)(g * Nn + t) * Fdim;
  #pragma unroll
  for (int c = 0; c < Fdim; c++) dp[c] = acc[c] / 100.0f;
}

// ---------- neighbor-mean over 100, C=128 ----------
__global__ void gm128_kernel(const float* __restrict__ src, const int* __restrict__ nbr,
                             float* __restrict__ dst) {
  __shared__ int ids[KG];
  int row = blockIdx.x; int g = row >> 9; int t = threadIdx.x;  // 128
  if (t < KG) ids[t] = nbr[(size_t)row * KG + t];
  __syncthreads();
  const float* sp = src + (size_t)g * Nn * Wd;
  float acc = 0.0f;
  #pragma unroll 4
  for (int k = 0; k < KG; k++) acc += sp[ids[k] * Wd + t];
  dst[(size_t)row * Wd + t] = acc / 100.0f;
}

// ---------- out = lrelu(in0@W[0] + in1@W[1] + in2@W[2] + b) ----------
__global__ void proj3_kernel(const float* __restrict__ in0, const float* __restrict__ in1,
                             const float* __restrict__ in2, const void* __restrict__ Wt_,
                             const void* __restrict__ bt_, float* __restrict__ out, int C,
                             long Woff, long boff, const int* __restrict__ flag) {
  __shared__ float s0[8 * 128], s1[8 * 128], s2[8 * 128];
  int t = threadIdx.x;  // 128
  int node0 = blockIdx.x * 8;
  int f32 = *flag;
  int nC = 8 * C;
  for (int idx = t; idx < nC; idx += 128) {
    s0[idx] = in0[(size_t)node0 * C + idx];
    s1[idx] = in1[(size_t)node0 * C + idx];
    s2[idx] = in2[(size_t)node0 * C + idx];
  }
  __syncthreads();
  float acc[8] = {0, 0, 0, 0, 0, 0, 0, 0};
  float bd;
  if (f32) {
    const float* W = (const float*)Wt_ + Woff;
    for (int c = 0; c < C; c++) {
      float w0 = W[c * 128 + t], w1 = W[(C + c) * 128 + t], w2 = W[(2 * C + c) * 128 + t];
      #pragma unroll
      for (int n = 0; n < 8; n++)
        acc[n] += s0[n * C + c] * w0 + s1[n * C + c] * w1 + s2[n * C + c] * w2;
    }
    bd = ((const float*)bt_ + boff)[t];
  } else {
    const bf16* W = (const bf16*)Wt_ + Woff;
    for (int c = 0; c < C; c++) {
      float w0 = b2f(W[c * 128 + t]), w1 = b2f(W[(C + c) * 128 + t]), w2 = b2f(W[(2 * C + c) * 128 + t]);
      #pragma unroll
      for (int n = 0; n < 8; n++)
        acc[n] += s0[n * C + c] * w0 + s1[n * C + c] * w1 + s2[n * C + c] * w2;
    }
    bd = b2f(((const bf16*)bt_ + boff)[t]);
  }
  #pragma unroll
  for (int n = 0; n < 8; n++)
    out[(size_t)(node0 + n) * 128 + t] = lrelu(acc[n] + bd);
}

// ---------- u = in@W[0:C], v = in@W[C:2C] ----------
__global__ void proj_dual_kernel(const float* __restrict__ in, const void* __restrict__ Wt_,
                                 float* __restrict__ u, float* __restrict__ v, int C,
                                 long Woff, const int* __restrict__ flag) {
  __shared__ float s0[8 * 128];
  int t = threadIdx.x; int node0 = blockIdx.x * 8;
  int f32 = *flag;
  for (int idx = t; idx < 8 * C; idx += 128) s0[idx] = in[(size_t)node0 * C + idx];
  __syncthreads();
  float au[8] = {0, 0, 0, 0, 0, 0, 0, 0};
  float av[8] = {0, 0, 0, 0, 0, 0, 0, 0};
  if (f32) {
    const float* W = (const float*)Wt_ + Woff;
    for (int c = 0; c < C; c++) {
      float wa = W[c * 128 + t], wb = W[(C + c) * 128 + t];
      #pragma unroll
      for (int n = 0; n < 8; n++) { float x = s0[n * C + c]; au[n] += x * wa; av[n] += x * wb; }
    }
  } else {
    const bf16* W = (const bf16*)Wt_ + Woff;
    for (int c = 0; c < C; c++) {
      float wa = b2f(W[c * 128 + t]), wb = b2f(W[(C + c) * 128 + t]);
      #pragma unroll
      for (int n = 0; n < 8; n++) { float x = s0[n * C + c]; au[n] += x * wa; av[n] += x * wb; }
    }
  }
  #pragma unroll
  for (int n = 0; n < 8; n++) {
    u[(size_t)(node0 + n) * 128 + t] = au[n];
    v[(size_t)(node0 + n) * 128 + t] = av[n];
  }
}

// ---------- edgeconv1 ----------
__global__ void edge_mlp1_kernel(const float* __restrict__ u, const float* __restrict__ v,
                                 const int* __restrict__ nbrp, const void* __restrict__ W2_,
                                 const void* __restrict__ b1_, const void* __restrict__ b2_,
                                 float* __restrict__ y, const int* __restrict__ flag) {
  __shared__ float tl[8][3][128];
  int t = threadIdx.x; int node0 = blockIdx.x * 8; int g = node0 >> 9;
  int f32 = *flag;
  float b1d;
  if (f32) b1d = ((const float*)b1_)[t]; else b1d = b2f(((const bf16*)b1_)[t]);
  for (int n = 0; n < 8; n++) {
    int row = node0 + n;
    float ui = u[(size_t)row * 128 + t], vi = v[(size_t)row * 128 + t];
    #pragma unroll
    for (int k = 0; k < 3; k++) {
      int j = nbrp[row * 3 + k];
      tl[n][k][t] = lrelu(ui + v[(size_t)(g * Nn + j) * 128 + t] - vi + b1d);
    }
  }
  __syncthreads();
  float acc[8][3];
  #pragma unroll
  for (int n = 0; n < 8; n++)
    #pragma unroll
    for (int k = 0; k < 3; k++) acc[n][k] = 0.0f;
  if (f32) {
    const float* W = (const float*)W2_;
    for (int c = 0; c < 128; c++) {
      float w = W[c * 128 + t];
      #pragma unroll
      for (int n = 0; n < 8; n++)
        #pragma unroll
        for (int k = 0; k < 3; k++) acc[n][k] += tl[n][k][c] * w;
    }
  } else {
    const bf16* W = (const bf16*)W2_;
    for (int c = 0; c < 128; c++) {
      float w = b2f(W[c * 128 + t]);
      #pragma unroll
      for (int n = 0; n < 8; n++)
        #pragma unroll
        for (int k = 0; k < 3; k++) acc[n][k] += tl[n][k][c] * w;
    }
  }
  float b2d;
  if (f32) b2d = ((const float*)b2_)[t]; else b2d = b2f(((const bf16*)b2_)[t]);
  #pragma unroll
  for (int n = 0; n < 8; n++) {
    float m = lrelu(acc[n][0] + b2d);
    m = fmaxf(m, lrelu(acc[n][1] + b2d));
    m = fmaxf(m, lrelu(acc[n][2] + b2d));
    y[(size_t)(node0 + n) * 128 + t] = m;
  }
}

// ---------- edgeconv2/3 ----------
__global__ void edge_max_kernel(const float* __restrict__ u, const float* __restrict__ v,
                                const int* __restrict__ nbrp, const void* __restrict__ bias_,
                                float* __restrict__ y, long boff, const int* __restrict__ flag) {
  int row = blockIdx.x; int g = row >> 9; int t = threadIdx.x;  // 128
  float ui = u[(size_t)row * 128 + t], vi = v[(size_t)row * 128 + t];
  float bd;
  if (*flag) bd = ((const float*)bias_ + boff)[t]; else bd = b2f(((const bf16*)bias_ + boff)[t]);
  float m = -3.4e38f;
  #pragma unroll
  for (int k = 0; k < 3; k++) {
    int j = nbrp[row * 3 + k];
    m = fmaxf(m, lrelu(ui - vi + v[(size_t)(g * Nn + j) * 128 + t] + bd));
  }
  y[(size_t)row * 128 + t] = m;
}

// ---------- squared norms ----------
__global__ void sqn_kernel(const float* __restrict__ y, float* __restrict__ sqn) {
  int row = blockIdx.x; int t = threadIdx.x;  // 64
  float a = y[(size_t)row * 128 + t], b = y[(size_t)row * 128 + t + 64];
  float s = a * a + b * b;
  #pragma unroll
  for (int off = 32; off > 0; off >>= 1) s += __shfl_down(s, off);
  if (t == 0) sqn[row] = s;
}

// ---------- chunked Gram matrix: G[gl] = Y[g0+gl] Y[g0+gl]^T ----------
__global__ void gram_kernel(const float* __restrict__ y, float* __restrict__ G, int g0) {
  __shared__ float As[64][17], Bs[64][17];
  int bid = blockIdx.x;
  int gl = bid >> 6; int tt = bid & 63; int ti = tt >> 3; int tj = tt & 7;
  int g = g0 + gl;
  int t = threadIdx.x; int tx = t & 15, ty = t >> 4;
  const float* Yg = y + (size_t)g * Nn * Wd;
  float* Gg = G + (size_t)gl * Nn * Nn;
  float c[4][4];
  #pragma unroll
  for (int p = 0; p < 4; p++)
    #pragma unroll
    for (int q = 0; q < 4; q++) c[p][q] = 0.0f;
  for (int k0 = 0; k0 < 128; k0 += 16) {
    for (int idx = t; idx < 1024; idx += 256) {
      int r = idx >> 4, cc = idx & 15;
      As[r][cc] = Yg[(ti * 64 + r) * 128 + k0 + cc];
      Bs[r][cc] = Yg[(tj * 64 + r) * 128 + k0 + cc];
    }
    __syncthreads();
    for (int kk = 0; kk < 16; kk++) {
      float a[4], bb[4];
      #pragma unroll
      for (int p = 0; p < 4; p++) a[p] = As[ty * 4 + p][kk];
      #pragma unroll
      for (int q = 0; q < 4; q++) bb[q] = Bs[tx * 4 + q][kk];
      #pragma unroll
      for (int p = 0; p < 4; p++)
        #pragma unroll
        for (int q = 0; q < 4; q++) c[p][q] += a[p] * bb[q];
    }
    __syncthreads();
  }
  #pragma unroll
  for (int p = 0; p < 4; p++)
    #pragma unroll
    for (int q = 0; q < 4; q++)
      Gg[(size_t)(ti * 64 + ty * 4 + p) * Nn + tj * 64 + tx * 4 + q] = c[p][q];
}

// ---------- mean+max pool ----------
__global__ void pool_kernel(const float* __restrict__ h, float* __restrict__ z,
                            int meanoff, int maxoff) {
  __shared__ float sm[4][128], sx[4][128];
  int g = blockIdx.x; int t = threadIdx.x;  // 512
  int c = t & 127, q = t >> 7;
  const float* hg = h + (size_t)g * Nn * Wd;
  float s = 0.0f, m = -3.4e38f;
  for (int n = q * 128; n < q * 128 + 128; n++) {
    float vv = hg[n * 128 + c];
    s += vv; m = fmaxf(m, vv);
  }
  sm[q][c] = s; sx[q][c] = m;
  __syncthreads();
  if (q == 0) {
    s = sm[0][c] + sm[1][c] + sm[2][c] + sm[3][c];
    m = fmaxf(fmaxf(sx[0][c], sx[1][c]), fmaxf(sx[2][c], sx[3][c]));
    z[g * DIM2 + meanoff + c] = s / 512.0f;
    z[g * DIM2 + maxoff + c] = m;
  }
}

// ---------- BatchNorm1d (batch stats), in place ----------
__global__ void bn_kernel(float* __restrict__ z, const void* __restrict__ gamma,
                          const void* __restrict__ beta, const int* __restrict__ flag) {
  int c = blockIdx.x * 256 + threadIdx.x;
  if (c >= DIM2) return;
  float s = 0.0f;
  for (int r = 0; r < Bg; r++) s += z[r * DIM2 + c];
  float mu = s / 32.0f;
  float v = 0.0f;
  for (int r = 0; r < Bg; r++) { float d = z[r * DIM2 + c] - mu; v += d * d; }
  float var = v / 32.0f;
  float gm, bt;
  if (*flag) { gm = ((const float*)gamma)[c]; bt = ((const float*)beta)[c]; }
  else       { gm = b2f(((const bf16*)gamma)[c]); bt = b2f(((const bf16*)beta)[c]); }
  float scale = gm / sqrtf(var + 1e-5f);
  for (int r = 0; r < Bg; r++) z[r * DIM2 + c] = (z[r * DIM2 + c] - mu) * scale + bt;
}

// ---------- head linear ----------
__global__ void hl_kernel(const float* __restrict__ in, const void* __restrict__ Wt_,
                          const void* __restrict__ bt_, float* __restrict__ out,
                          long Woff, long boff, const int* __restrict__ flag) {
  __shared__ float a[32 * 129];
  int t = threadIdx.x; int dcol = blockIdx.x * 8 + (t >> 5); int r = t & 31;
  int f32 = *flag;
  float acc = 0.0f;
  for (int k0 = 0; k0 < DIM2; k0 += 128) {
    for (int idx = t; idx < 4096; idx += 256) {
      int rr = idx >> 7, kk = idx & 127;
      a[rr * 129 + kk] = in[rr * DIM2 + k0 + kk];
    }
    __syncthreads();
    if (f32) {
      const float* W = (const float*)Wt_ + Woff;
      for (int kk = 0; kk < 128; kk++)
        acc += a[r * 129 + kk] * W[(size_t)(k0 + kk) * DIM2 + dcol];
    } else {
      const bf16* W = (const bf16*)Wt_ + Woff;
      for (int kk = 0; kk < 128; kk++)
        acc += a[r * 129 + kk] * b2f(W[(size_t)(k0 + kk) * DIM2 + dcol]);
    }
    __syncthreads();
  }
  float bd;
  if (f32) bd = ((const float*)bt_ + boff)[dcol]; else bd = b2f(((const bf16*)bt_ + boff)[dcol]);
  out[r * DIM2 + dcol] = lrelu(acc + bd);
}

// ---------- final ----------
__global__ void final_kernel(const float* __restrict__ zin, const void* __restrict__ outW,
                             const void* __restrict__ outb, void* __restrict__ out,
                             const int* __restrict__ flag) {
  __shared__ float red[256];
  int r = blockIdx.x, t = threadIdx.x;
  int f32 = *flag;
  float acc = 0.0f;
  if (f32) {
    const float* W = (const float*)outW;
    for (int c = t; c < DIM2; c += 256) acc += zin[r * DIM2 + c] * W[c];
  } else {
    const bf16* W = (const bf16*)outW;
    for (int c = t; c < DIM2; c += 256) acc += zin[r * DIM2 + c] * b2f(W[c]);
  }
  red[t] = acc; __syncthreads();
  for (int s = 128; s > 0; s >>= 1) { if (t < s) red[t] += red[t + s]; __syncthreads(); }
  if (t == 0) {
    float ob;
    if (f32) ob = ((const float*)outb)[0]; else ob = b2f(((const bf16*)outb)[0]);
    float val = red[0] + ob;
    if (f32) ((float*)out)[r] = val;
    else     ((bf16*)out)[r] = __float2bfloat16(val);
  }
}

extern "C" void kernel_launch(void* const* d_in, const int* in_sizes, int n_in,
                              void* d_out, int out_size, void* d_ws, size_t ws_size,
                              hipStream_t stream) {
  const void* x      = d_in[0];
  const void* tag1_W = d_in[2];
  const void* tag1_b = d_in[3];
  const void* tag_W  = d_in[4];
  const void* tag_b  = d_in[5];
  const void* p1_W1  = d_in[6];
  const void* p1_b1  = d_in[7];
  const void* p1_W2  = d_in[8];
  const void* p1_b2  = d_in[9];
  const void* pf_W   = d_in[10];
  const void* pf_b   = d_in[11];
  const void* bn_g   = d_in[12];
  const void* bn_b   = d_in[13];
  const void* lin_W  = d_in[14];
  const void* lin_b  = d_in[15];
  const void* out_W  = d_in[16];
  const void* out_b  = d_in[17];

  // ---- workspace layout: total 10,485,776 floats ≈ 40 MB ----
  float* ws = (float*)d_ws;
  float* XF   = ws + 0;                 // 98304
  float* M16  = ws + 98304;             // 98304
  float* M26  = ws + 196608;            // 98304
  float* Z    = ws + 294912;            // 49152
  float* ZB   = ws + 344064;            // 49152
  float* SQ   = ws + 393216;            // 16384
  int*   FLAG = (int*)(ws + 409600);    // 16
  int*   NBRP = (int*)(ws + 409616);    // 49152 ints
  int*   NBRG = (int*)(ws + 458768);    // 1,638,400 ints -> ends 2,097,168
  float* S0   = ws + 2097168;           // 4 slots x 2,097,152 floats (8 MB each)
  float* S1   = ws + 4194320;           // S0+S1 contiguous -> 16 MB G region
  float* S2   = ws + 6291472;
  float* S3   = ws + 8388624;           // ends 10,485,776 floats

  detect_kernel<<<1, 64, 0, stream>>>((const unsigned short*)x, FLAG);
  convert_kernel<<<384, 256, 0, stream>>>(x, XF, Bg * Nn * Fdim, FLAG);
  knn100_kernel<<<Bg * Nn, 256, 0, stream>>>(XF, NBRG);
  knn3_x_kernel<<<Bg * Nn / 4, 256, 0, stream>>>(XF, NBRP);

  // ---- TAG branch: Hb=S0, M1=S1, M2=S2, HN=S3 ----
  gm6_kernel<<<Bg, 512, 0, stream>>>(XF, NBRG, M16);
  gm6_kernel<<<Bg, 512, 0, stream>>>(M16, NBRG, M26);
  proj3_kernel<<<2048, 128, 0, stream>>>(XF, M16, M26, tag1_W, tag1_b, S0, 6, 0, 0, FLAG);
  pool_kernel<<<Bg, 512, 0, stream>>>(S0, Z, 0, 128);

  gm128_kernel<<<Bg * Nn, 128, 0, stream>>>(S0, NBRG, S1);
  gm128_kernel<<<Bg * Nn, 128, 0, stream>>>(S1, NBRG, S2);
  proj3_kernel<<<2048, 128, 0, stream>>>(S0, S1, S2, tag_W, tag_b, S3, 128, 0, 0, FLAG);
  pool_kernel<<<Bg, 512, 0, stream>>>(S3, Z, 256, 384);

  gm128_kernel<<<Bg * Nn, 128, 0, stream>>>(S3, NBRG, S1);
  gm128_kernel<<<Bg * Nn, 128, 0, stream>>>(S1, NBRG, S2);
  proj3_kernel<<<2048, 128, 0, stream>>>(S3, S1, S2, tag_W, tag_b, S0, 128,
                                         3L * 128 * 128, 128, FLAG);
  pool_kernel<<<Bg, 512, 0, stream>>>(S0, Z, 512, 640);

  // ---- point branch: U=S0, V=S1; Y rotates S2/S3; G uses S0+S1 (16 MB) ----
  proj_dual_kernel<<<2048, 128, 0, stream>>>(XF, p1_W1, S0, S1, 6, 0, FLAG);
  edge_mlp1_kernel<<<2048, 128, 0, stream>>>(S0, S1, NBRP, p1_W2, p1_b1, p1_b2, S2, FLAG);  // Y0=S2
  pool_kernel<<<Bg, 512, 0, stream>>>(S2, Z, 768, 1152);

  sqn_kernel<<<Bg * Nn, 64, 0, stream>>>(S2, SQ);
  for (int c = 0; c < Bg; c += GC16) {             // G=S0+S1 (U,V dead)
    gram_kernel<<<GC16 * 64, 256, 0, stream>>>(S2, S0, c);
    knn3_gram_kernel<<<GC16 * Nn / 4, 256, 0, stream>>>(S0, SQ, NBRP, c);
  }
  proj_dual_kernel<<<2048, 128, 0, stream>>>(S2, pf_W, S0, S1, 128, 0, FLAG);  // G dead
  edge_max_kernel<<<Bg * Nn, 128, 0, stream>>>(S0, S1, NBRP, pf_b, S3, 0, FLAG);  // Y1=S3
  pool_kernel<<<Bg, 512, 0, stream>>>(S3, Z, 896, 1280);

  sqn_kernel<<<Bg * Nn, 64, 0, stream>>>(S3, SQ);
  for (int c = 0; c < Bg; c += GC16) {             // G=S0+S1 (U,V dead)
    gram_kernel<<<GC16 * 64, 256, 0, stream>>>(S3, S0, c);
    knn3_gram_kernel<<<GC16 * Nn / 4, 256, 0, stream>>>(S0, SQ, NBRP, c);
  }
  proj_dual_kernel<<<2048, 128, 0, stream>>>(S3, pf_W, S0, S1, 128, 256L * 128, FLAG);  // G dead
  edge_max_kernel<<<Bg * Nn, 128, 0, stream>>>(S0, S1, NBRP, pf_b, S2, 128, FLAG);  // Y2=S2 (Y0 dead)
  pool_kernel<<<Bg, 512, 0, stream>>>(S2, Z, 1024, 1408);

  // ---- head ----
  bn_kernel<<<6, 256, 0, stream>>>(Z, bn_g, bn_b, FLAG);
  hl_kernel<<<192, 256, 0, stream>>>(Z, lin_W, lin_b, ZB, 0L, 0L, FLAG);
  hl_kernel<<<192, 256, 0, stream>>>(ZB, lin_W, lin_b, Z, 1L * DIM2 * DIM2, 1L * DIM2, FLAG);
  hl_kernel<<<192, 256, 0, stream>>>(Z, lin_W, lin_b, ZB, 2L * DIM2 * DIM2, 2L * DIM2, FLAG);
  hl_kernel<<<192, 256, 0, stream>>>(ZB, lin_W, lin_b, Z, 3L * DIM2 * DIM2, 3L * DIM2, FLAG);
  hl_kernel<<<192, 256, 0, stream>>>(Z, lin_W, lin_b, ZB, 4L * DIM2 * DIM2, 4L * DIM2, FLAG);
  final_kernel<<<Bg, 256, 0, stream>>>(ZB, out_W, out_b, d_out, FLAG);
}

// Round 5
// 1772.190 us; speedup vs baseline: 1.1967x; 1.0624x over previous
//
#include <hip/hip_runtime.h>
#include <hip/hip_bf16.h>

#define Bg 32
#define Nn 512
#define Fdim 6
#define Wd 128
#define KG 100
#define KP 3
#define DIM2 1536
#define GC16 16

typedef __hip_bfloat16 bf16;

__device__ __forceinline__ float b2f(bf16 v) { return __bfloat162float(v); }
__device__ __forceinline__ float lrelu(float v) { return v > 0.0f ? v : 0.01f * v; }

// ---------- dtype detection (f32=1 / bf16=0), from low-half u16 bit patterns ----------
__global__ void detect_kernel(const unsigned short* __restrict__ x, int* __restrict__ flag) {
  if (threadIdx.x == 0 && blockIdx.x == 0) {
    int big = 0;
    for (int i = 0; i < 512; i += 2) {
      unsigned short u = x[i];
      int e = (u >> 7) & 0xFF;
      if (e >= 140) big++;
    }
    *flag = (big > 20) ? 1 : 0;
  }
}

// ---------- convert x -> f32 ----------
__global__ void convert_kernel(const void* __restrict__ x, float* __restrict__ xf, int n,
                               const int* __restrict__ flag) {
  int i = blockIdx.x * 256 + threadIdx.x;
  if (i >= n) return;
  if (*flag) xf[i] = ((const float*)x)[i];
  else       xf[i] = b2f(((const bf16*)x)[i]);
}

// ---------- sorted-3 insertion on u64 keys ----------
__device__ __forceinline__ void ins3(unsigned long long key, unsigned long long& k0,
                                     unsigned long long& k1, unsigned long long& k2) {
  if (key < k2) {
    if (key < k1) {
      k2 = k1;
      if (key < k0) { k1 = k0; k0 = key; } else k1 = key;
    } else k2 = key;
  }
}

// ---------- kNN k=100: one wave per row, ballot radix-select, no LDS select state ----------
__global__ void knn100_kernel(const float* __restrict__ xf, int* __restrict__ nbr) {
  __shared__ float xg[Nn * Fdim];
  int t = threadIdx.x; int w = t >> 6; int l = t & 63;
  int row0 = blockIdx.x * 4; int g = row0 >> 9;   // 4 rows (one per wave) per block
  const float* xp = xf + g * (Nn * Fdim);
  for (int idx = t; idx < Nn * Fdim; idx += 256) xg[idx] = xp[idx];
  __syncthreads();
  int i = (row0 & 511) + w;
  float xi[Fdim];
  #pragma unroll
  for (int c = 0; c < Fdim; c++) xi[c] = xg[i * Fdim + c];
  float sqi = 0.0f;
  #pragma unroll
  for (int c = 0; c < Fdim; c++) sqi += xi[c] * xi[c];
  unsigned m[8];
  #pragma unroll
  for (int ch = 0; ch < 8; ch++) {
    int j = ch * 64 + l;
    float dot = 0.0f, sqj = 0.0f;
    #pragma unroll
    for (int c = 0; c < Fdim; c++) { float v = xg[j * Fdim + c]; dot += xi[c] * v; sqj += v * v; }
    float d = sqi + sqj - 2.0f * dot;
    if (j == i) d += 1e10f;
    unsigned u = __float_as_uint(d);
    m[ch] = (u & 0x80000000u) ? ~u : (u | 0x80000000u);
  }
  // binary search for T = exact 100th-smallest key; invariant count(m < T) < 100
  unsigned T = 0u;
  for (int b = 31; b >= 0; b--) {
    unsigned mid = T | (1u << b);
    int c = 0;
    #pragma unroll
    for (int ch = 0; ch < 8; ch++) c += (m[ch] < mid) ? 1 : 0;
    #pragma unroll
    for (int off = 32; off >= 1; off >>= 1) c += __shfl_xor(c, off, 64);
    if (c < KG) T = mid;
  }
  int* outp = nbr + ((size_t)(g * Nn + i)) * KG;
  unsigned long long lmask = (1ull << l) - 1ull;
  int base = 0;
  #pragma unroll
  for (int ch = 0; ch < 8; ch++) {
    bool less = m[ch] < T;
    unsigned long long bal = __ballot(less);
    if (less) outp[base + __popcll(bal & lmask)] = ch * 64 + l;
    base += __popcll(bal);
  }
  int need = KG - base;   // fill remainder with m == T, smallest idx first (stable top_k)
  int eqb = 0;
  #pragma unroll
  for (int ch = 0; ch < 8; ch++) {
    bool eq = (m[ch] == T);
    unsigned long long bal = __ballot(eq);
    int gr = eqb + __popcll(bal & lmask);
    if (eq && gr < need) outp[base + gr] = ch * 64 + l;
    eqb += __popcll(bal);
  }
}

// ---------- kNN k=3 on coords: one wave per row, 4 rows/block ----------
__global__ void knn3_x_kernel(const float* __restrict__ xf, int* __restrict__ nbr) {
  __shared__ float xg[Nn * Fdim];
  int bid = blockIdx.x; int t = threadIdx.x; int w = t >> 6; int l = t & 63;
  int row0 = bid * 4; int g = row0 >> 9;
  const float* xp = xf + g * (Nn * Fdim);
  for (int idx = t; idx < Nn * Fdim; idx += 256) xg[idx] = xp[idx];
  __syncthreads();
  int i = (row0 & 511) + w;
  float xi[Fdim];
  #pragma unroll
  for (int c = 0; c < Fdim; c++) xi[c] = xg[i * Fdim + c];
  float sqi = 0.0f;
  #pragma unroll
  for (int c = 0; c < Fdim; c++) sqi += xi[c] * xi[c];
  unsigned long long k0 = ~0ull, k1 = ~0ull, k2 = ~0ull;
  #pragma unroll
  for (int ch = 0; ch < 8; ch++) {
    int j = ch * 64 + l;
    float dot = 0.0f, sqj = 0.0f;
    #pragma unroll
    for (int c = 0; c < Fdim; c++) { float v = xg[j * Fdim + c]; dot += xi[c] * v; sqj += v * v; }
    float d = sqi + sqj - 2.0f * dot;
    if (j == i) d += 1e10f;
    unsigned u = __float_as_uint(d);
    unsigned m = (u & 0x80000000u) ? ~u : (u | 0x80000000u);
    unsigned long long key = ((unsigned long long)m << 32) | (unsigned)j;
    ins3(key, k0, k1, k2);
  }
  #pragma unroll
  for (int off = 32; off >= 1; off >>= 1) {
    unsigned long long b0 = __shfl_xor(k0, off, 64);
    unsigned long long b1 = __shfl_xor(k1, off, 64);
    unsigned long long b2 = __shfl_xor(k2, off, 64);
    ins3(b0, k0, k1, k2); ins3(b1, k0, k1, k2); ins3(b2, k0, k1, k2);
  }
  if (l == 0) {
    int row = (g << 9) + i;
    nbr[row * 3 + 0] = (int)(k0 & 0xFFFFFFFFu);
    nbr[row * 3 + 1] = (int)(k1 & 0xFFFFFFFFu);
    nbr[row * 3 + 2] = (int)(k2 & 0xFFFFFFFFu);
  }
}

// ---------- kNN k=3 from chunked Gram (sq norms from G diagonal) ----------
__global__ void knn3_gram_kernel(const float* __restrict__ G, int* __restrict__ nbr, int g0) {
  __shared__ float sq[Nn];
  int bid = blockIdx.x; int t = threadIdx.x; int w = t >> 6; int l = t & 63;
  int lr0 = bid * 4; int gl = lr0 >> 9; int g = g0 + gl;
  const float* Gg = G + (size_t)gl * Nn * Nn;
  for (int idx = t; idx < Nn; idx += 256) sq[idx] = Gg[(size_t)idx * Nn + idx];
  __syncthreads();
  int i = (lr0 & 511) + w;
  float sqi = sq[i];
  const float* Gr = Gg + (size_t)i * Nn;
  unsigned long long k0 = ~0ull, k1 = ~0ull, k2 = ~0ull;
  #pragma unroll
  for (int ch = 0; ch < 8; ch++) {
    int j = ch * 64 + l;
    float d = sqi + sq[j] - 2.0f * Gr[j];
    if (j == i) d += 1e10f;
    unsigned u = __float_as_uint(d);
    unsigned m = (u & 0x80000000u) ? ~u : (u | 0x80000000u);
    unsigned long long key = ((unsigned long long)m << 32) | (unsigned)j;
    ins3(key, k0, k1, k2);
  }
  #pragma unroll
  for (int off = 32; off >= 1; off >>= 1) {
    unsigned long long b0 = __shfl_xor(k0, off, 64);
    unsigned long long b1 = __shfl_xor(k1, off, 64);
    unsigned long long b2 = __shfl_xor(k2, off, 64);
    ins3(b0, k0, k1, k2); ins3(b1, k0, k1, k2); ins3(b2, k0, k1, k2);
  }
  if (l == 0) {
    int row = g * Nn + i;
    nbr[row * 3 + 0] = (int)(k0 & 0xFFFFFFFFu);
    nbr[row * 3 + 1] = (int)(k1 & 0xFFFFFFFFu);
    nbr[row * 3 + 2] = (int)(k2 & 0xFFFFFFFFu);
  }
}

// ---------- neighbor-mean over 100, C=6 ----------
__global__ void gm6_kernel(const float* __restrict__ src, const int* __restrict__ nbr,
                           float* __restrict__ dst) {
  __shared__ float s[Nn * Fdim];
  int g = blockIdx.x; int t = threadIdx.x;  // 512
  const float* sp = src + g * (Nn * Fdim);
  for (int idx = t; idx < Nn * Fdim; idx += 512) s[idx] = sp[idx];
  __syncthreads();
  float acc[Fdim] = {0, 0, 0, 0, 0, 0};
  const int* nb = nbr + ((size_t)(g * Nn + t)) * KG;
  for (int k = 0; k < KG; k++) {
    int j = nb[k];
    #pragma unroll
    for (int c = 0; c < Fdim; c++) acc[c] += s[j * Fdim + c];
  }
  float* dp = dst + (size_t)(g * Nn + t) * Fdim;
  #pragma unroll
  for (int c = 0; c < Fdim; c++) dp[c] = acc[c] / 100.0f;
}

// ---------- neighbor-mean over 100, C=128 ----------
__global__ void gm128_kernel(const float* __restrict__ src, const int* __restrict__ nbr,
                             float* __restrict__ dst) {
  __shared__ int ids[KG];
  int row = blockIdx.x; int g = row >> 9; int t = threadIdx.x;  // 128
  if (t < KG) ids[t] = nbr[(size_t)row * KG + t];
  __syncthreads();
  const float* sp = src + (size_t)g * Nn * Wd;
  float acc = 0.0f;
  #pragma unroll 4
  for (int k = 0; k < KG; k++) acc += sp[ids[k] * Wd + t];
  dst[(size_t)row * Wd + t] = acc / 100.0f;
}

// ---------- out = lrelu(in0@W[0] + in1@W[1] + in2@W[2] + b) ----------
__global__ void proj3_kernel(const float* __restrict__ in0, const float* __restrict__ in1,
                             const float* __restrict__ in2, const void* __restrict__ Wt_,
                             const void* __restrict__ bt_, float* __restrict__ out, int C,
                             long Woff, long boff, const int* __restrict__ flag) {
  __shared__ float s0[8 * 128], s1[8 * 128], s2[8 * 128];
  int t = threadIdx.x;  // 128
  int node0 = blockIdx.x * 8;
  int f32 = *flag;
  int nC = 8 * C;
  for (int idx = t; idx < nC; idx += 128) {
    s0[idx] = in0[(size_t)node0 * C + idx];
    s1[idx] = in1[(size_t)node0 * C + idx];
    s2[idx] = in2[(size_t)node0 * C + idx];
  }
  __syncthreads();
  float acc[8] = {0, 0, 0, 0, 0, 0, 0, 0};
  float bd;
  if (f32) {
    const float* W = (const float*)Wt_ + Woff;
    for (int c = 0; c < C; c++) {
      float w0 = W[c * 128 + t], w1 = W[(C + c) * 128 + t], w2 = W[(2 * C + c) * 128 + t];
      #pragma unroll
      for (int n = 0; n < 8; n++)
        acc[n] += s0[n * C + c] * w0 + s1[n * C + c] * w1 + s2[n * C + c] * w2;
    }
    bd = ((const float*)bt_ + boff)[t];
  } else {
    const bf16* W = (const bf16*)Wt_ + Woff;
    for (int c = 0; c < C; c++) {
      float w0 = b2f(W[c * 128 + t]), w1 = b2f(W[(C + c) * 128 + t]), w2 = b2f(W[(2 * C + c) * 128 + t]);
      #pragma unroll
      for (int n = 0; n < 8; n++)
        acc[n] += s0[n * C + c] * w0 + s1[n * C + c] * w1 + s2[n * C + c] * w2;
    }
    bd = b2f(((const bf16*)bt_ + boff)[t]);
  }
  #pragma unroll
  for (int n = 0; n < 8; n++)
    out[(size_t)(node0 + n) * 128 + t] = lrelu(acc[n] + bd);
}

// ---------- u = in@W[0:C], v = in@W[C:2C] ----------
__global__ void proj_dual_kernel(const float* __restrict__ in, const void* __restrict__ Wt_,
                                 float* __restrict__ u, float* __restrict__ v, int C,
                                 long Woff, const int* __restrict__ flag) {
  __shared__ float s0[8 * 128];
  int t = threadIdx.x; int node0 = blockIdx.x * 8;
  int f32 = *flag;
  for (int idx = t; idx < 8 * C; idx += 128) s0[idx] = in[(size_t)node0 * C + idx];
  __syncthreads();
  float au[8] = {0, 0, 0, 0, 0, 0, 0, 0};
  float av[8] = {0, 0, 0, 0, 0, 0, 0, 0};
  if (f32) {
    const float* W = (const float*)Wt_ + Woff;
    for (int c = 0; c < C; c++) {
      float wa = W[c * 128 + t], wb = W[(C + c) * 128 + t];
      #pragma unroll
      for (int n = 0; n < 8; n++) { float x = s0[n * C + c]; au[n] += x * wa; av[n] += x * wb; }
    }
  } else {
    const bf16* W = (const bf16*)Wt_ + Woff;
    for (int c = 0; c < C; c++) {
      float wa = b2f(W[c * 128 + t]), wb = b2f(W[(C + c) * 128 + t]);
      #pragma unroll
      for (int n = 0; n < 8; n++) { float x = s0[n * C + c]; au[n] += x * wa; av[n] += x * wb; }
    }
  }
  #pragma unroll
  for (int n = 0; n < 8; n++) {
    u[(size_t)(node0 + n) * 128 + t] = au[n];
    v[(size_t)(node0 + n) * 128 + t] = av[n];
  }
}

// ---------- edgeconv1 ----------
__global__ void edge_mlp1_kernel(const float* __restrict__ u, const float* __restrict__ v,
                                 const int* __restrict__ nbrp, const void* __restrict__ W2_,
                                 const void* __restrict__ b1_, const void* __restrict__ b2_,
                                 float* __restrict__ y, const int* __restrict__ flag) {
  __shared__ float tl[8][3][128];
  int t = threadIdx.x; int node0 = blockIdx.x * 8; int g = node0 >> 9;
  int f32 = *flag;
  float b1d;
  if (f32) b1d = ((const float*)b1_)[t]; else b1d = b2f(((const bf16*)b1_)[t]);
  for (int n = 0; n < 8; n++) {
    int row = node0 + n;
    float ui = u[(size_t)row * 128 + t], vi = v[(size_t)row * 128 + t];
    #pragma unroll
    for (int k = 0; k < 3; k++) {
      int j = nbrp[row * 3 + k];
      tl[n][k][t] = lrelu(ui + v[(size_t)(g * Nn + j) * 128 + t] - vi + b1d);
    }
  }
  __syncthreads();
  float acc[8][3];
  #pragma unroll
  for (int n = 0; n < 8; n++)
    #pragma unroll
    for (int k = 0; k < 3; k++) acc[n][k] = 0.0f;
  if (f32) {
    const float* W = (const float*)W2_;
    for (int c = 0; c < 128; c++) {
      float w = W[c * 128 + t];
      #pragma unroll
      for (int n = 0; n < 8; n++)
        #pragma unroll
        for (int k = 0; k < 3; k++) acc[n][k] += tl[n][k][c] * w;
    }
  } else {
    const bf16* W = (const bf16*)W2_;
    for (int c = 0; c < 128; c++) {
      float w = b2f(W[c * 128 + t]);
      #pragma unroll
      for (int n = 0; n < 8; n++)
        #pragma unroll
        for (int k = 0; k < 3; k++) acc[n][k] += tl[n][k][c] * w;
    }
  }
  float b2d;
  if (f32) b2d = ((const float*)b2_)[t]; else b2d = b2f(((const bf16*)b2_)[t]);
  #pragma unroll
  for (int n = 0; n < 8; n++) {
    float m = lrelu(acc[n][0] + b2d);
    m = fmaxf(m, lrelu(acc[n][1] + b2d));
    m = fmaxf(m, lrelu(acc[n][2] + b2d));
    y[(size_t)(node0 + n) * 128 + t] = m;
  }
}

// ---------- edgeconv2/3 ----------
__global__ void edge_max_kernel(const float* __restrict__ u, const float* __restrict__ v,
                                const int* __restrict__ nbrp, const void* __restrict__ bias_,
                                float* __restrict__ y, long boff, const int* __restrict__ flag) {
  int row = blockIdx.x; int g = row >> 9; int t = threadIdx.x;  // 128
  float ui = u[(size_t)row * 128 + t], vi = v[(size_t)row * 128 + t];
  float bd;
  if (*flag) bd = ((const float*)bias_ + boff)[t]; else bd = b2f(((const bf16*)bias_ + boff)[t]);
  float m = -3.4e38f;
  #pragma unroll
  for (int k = 0; k < 3; k++) {
    int j = nbrp[row * 3 + k];
    m = fmaxf(m, lrelu(ui - vi + v[(size_t)(g * Nn + j) * 128 + t] + bd));
  }
  y[(size_t)row * 128 + t] = m;
}

// ---------- chunked Gram matrix: G[gl] = Y[g0+gl] Y[g0+gl]^T ----------
__global__ void gram_kernel(const float* __restrict__ y, float* __restrict__ G, int g0) {
  __shared__ float As[64][17], Bs[64][17];
  int bid = blockIdx.x;
  int gl = bid >> 6; int tt = bid & 63; int ti = tt >> 3; int tj = tt & 7;
  int g = g0 + gl;
  int t = threadIdx.x; int tx = t & 15, ty = t >> 4;
  const float* Yg = y + (size_t)g * Nn * Wd;
  float* Gg = G + (size_t)gl * Nn * Nn;
  float c[4][4];
  #pragma unroll
  for (int p = 0; p < 4; p++)
    #pragma unroll
    for (int q = 0; q < 4; q++) c[p][q] = 0.0f;
  for (int k0 = 0; k0 < 128; k0 += 16) {
    for (int idx = t; idx < 1024; idx += 256) {
      int r = idx >> 4, cc = idx & 15;
      As[r][cc] = Yg[(ti * 64 + r) * 128 + k0 + cc];
      Bs[r][cc] = Yg[(tj * 64 + r) * 128 + k0 + cc];
    }
    __syncthreads();
    for (int kk = 0; kk < 16; kk++) {
      float a[4], bb[4];
      #pragma unroll
      for (int p = 0; p < 4; p++) a[p] = As[ty * 4 + p][kk];
      #pragma unroll
      for (int q = 0; q < 4; q++) bb[q] = Bs[tx * 4 + q][kk];
      #pragma unroll
      for (int p = 0; p < 4; p++)
        #pragma unroll
        for (int q = 0; q < 4; q++) c[p][q] += a[p] * bb[q];
    }
    __syncthreads();
  }
  #pragma unroll
  for (int p = 0; p < 4; p++)
    #pragma unroll
    for (int q = 0; q < 4; q++)
      Gg[(size_t)(ti * 64 + ty * 4 + p) * Nn + tj * 64 + tx * 4 + q] = c[p][q];
}

// ---------- mean+max pool ----------
__global__ void pool_kernel(const float* __restrict__ h, float* __restrict__ z,
                            int meanoff, int maxoff) {
  __shared__ float sm[4][128], sx[4][128];
  int g = blockIdx.x; int t = threadIdx.x;  // 512
  int c = t & 127, q = t >> 7;
  const float* hg = h + (size_t)g * Nn * Wd;
  float s = 0.0f, m = -3.4e38f;
  for (int n = q * 128; n < q * 128 + 128; n++) {
    float vv = hg[n * 128 + c];
    s += vv; m = fmaxf(m, vv);
  }
  sm[q][c] = s; sx[q][c] = m;
  __syncthreads();
  if (q == 0) {
    s = sm[0][c] + sm[1][c] + sm[2][c] + sm[3][c];
    m = fmaxf(fmaxf(sx[0][c], sx[1][c]), fmaxf(sx[2][c], sx[3][c]));
    z[g * DIM2 + meanoff + c] = s / 512.0f;
    z[g * DIM2 + maxoff + c] = m;
  }
}

// ---------- BatchNorm1d (batch stats), in place ----------
__global__ void bn_kernel(float* __restrict__ z, const void* __restrict__ gamma,
                          const void* __restrict__ beta, const int* __restrict__ flag) {
  int c = blockIdx.x * 256 + threadIdx.x;
  if (c >= DIM2) return;
  float s = 0.0f;
  for (int r = 0; r < Bg; r++) s += z[r * DIM2 + c];
  float mu = s / 32.0f;
  float v = 0.0f;
  for (int r = 0; r < Bg; r++) { float d = z[r * DIM2 + c] - mu; v += d * d; }
  float var = v / 32.0f;
  float gm, bt;
  if (*flag) { gm = ((const float*)gamma)[c]; bt = ((const float*)beta)[c]; }
  else       { gm = b2f(((const bf16*)gamma)[c]); bt = b2f(((const bf16*)beta)[c]); }
  float scale = gm / sqrtf(var + 1e-5f);
  for (int r = 0; r < Bg; r++) z[r * DIM2 + c] = (z[r * DIM2 + c] - mu) * scale + bt;
}

// ---------- head linear ----------
__global__ void hl_kernel(const float* __restrict__ in, const void* __restrict__ Wt_,
                          const void* __restrict__ bt_, float* __restrict__ out,
                          long Woff, long boff, const int* __restrict__ flag) {
  __shared__ float a[32 * 129];
  int t = threadIdx.x; int dcol = blockIdx.x * 8 + (t >> 5); int r = t & 31;
  int f32 = *flag;
  float acc = 0.0f;
  for (int k0 = 0; k0 < DIM2; k0 += 128) {
    for (int idx = t; idx < 4096; idx += 256) {
      int rr = idx >> 7, kk = idx & 127;
      a[rr * 129 + kk] = in[rr * DIM2 + k0 + kk];
    }
    __syncthreads();
    if (f32) {
      const float* W = (const float*)Wt_ + Woff;
      for (int kk = 0; kk < 128; kk++)
        acc += a[r * 129 + kk] * W[(size_t)(k0 + kk) * DIM2 + dcol];
    } else {
      const bf16* W = (const bf16*)Wt_ + Woff;
      for (int kk = 0; kk < 128; kk++)
        acc += a[r * 129 + kk] * b2f(W[(size_t)(k0 + kk) * DIM2 + dcol]);
    }
    __syncthreads();
  }
  float bd;
  if (f32) bd = ((const float*)bt_ + boff)[dcol]; else bd = b2f(((const bf16*)bt_ + boff)[dcol]);
  out[r * DIM2 + dcol] = lrelu(acc + bd);
}

// ---------- final ----------
__global__ void final_kernel(const float* __restrict__ zin, const void* __restrict__ outW,
                             const void* __restrict__ outb, void* __restrict__ out,
                             const int* __restrict__ flag) {
  __shared__ float red[256];
  int r = blockIdx.x, t = threadIdx.x;
  int f32 = *flag;
  float acc = 0.0f;
  if (f32) {
    const float* W = (const float*)outW;
    for (int c = t; c < DIM2; c += 256) acc += zin[r * DIM2 + c] * W[c];
  } else {
    const bf16* W = (const bf16*)outW;
    for (int c = t; c < DIM2; c += 256) acc += zin[r * DIM2 + c] * b2f(W[c]);
  }
  red[t] = acc; __syncthreads();
  for (int s = 128; s > 0; s >>= 1) { if (t < s) red[t] += red[t + s]; __syncthreads(); }
  if (t == 0) {
    float ob;
    if (f32) ob = ((const float*)outb)[0]; else ob = b2f(((const bf16*)outb)[0]);
    float val = red[0] + ob;
    if (f32) ((float*)out)[r] = val;
    else     ((bf16*)out)[r] = __float2bfloat16(val);
  }
}

extern "C" void kernel_launch(void* const* d_in, const int* in_sizes, int n_in,
                              void* d_out, int out_size, void* d_ws, size_t ws_size,
                              hipStream_t stream) {
  const void* x      = d_in[0];
  const void* tag1_W = d_in[2];
  const void* tag1_b = d_in[3];
  const void* tag_W  = d_in[4];
  const void* tag_b  = d_in[5];
  const void* p1_W1  = d_in[6];
  const void* p1_b1  = d_in[7];
  const void* p1_W2  = d_in[8];
  const void* p1_b2  = d_in[9];
  const void* pf_W   = d_in[10];
  const void* pf_b   = d_in[11];
  const void* bn_g   = d_in[12];
  const void* bn_b   = d_in[13];
  const void* lin_W  = d_in[14];
  const void* lin_b  = d_in[15];
  const void* out_W  = d_in[16];
  const void* out_b  = d_in[17];

  // ---- workspace layout: total 10,485,776 floats ≈ 40 MB ----
  float* ws = (float*)d_ws;
  float* XF   = ws + 0;                 // 98304
  float* M16  = ws + 98304;             // 98304
  float* M26  = ws + 196608;            // 98304
  float* Z    = ws + 294912;            // 49152
  float* ZB   = ws + 344064;            // 49152
  int*   FLAG = (int*)(ws + 409600);    // 16
  int*   NBRP = (int*)(ws + 409616);    // 49152 ints
  int*   NBRG = (int*)(ws + 458768);    // 1,638,400 ints -> ends 2,097,168
  float* S0   = ws + 2097168;           // 4 slots x 2,097,152 floats (8 MB each)
  float* S1   = ws + 4194320;           // S0+S1 contiguous -> 16 MB G region
  float* S2   = ws + 6291472;
  float* S3   = ws + 8388624;           // ends 10,485,776 floats

  detect_kernel<<<1, 64, 0, stream>>>((const unsigned short*)x, FLAG);
  convert_kernel<<<384, 256, 0, stream>>>(x, XF, Bg * Nn * Fdim, FLAG);
  knn100_kernel<<<Bg * Nn / 4, 256, 0, stream>>>(XF, NBRG);
  knn3_x_kernel<<<Bg * Nn / 4, 256, 0, stream>>>(XF, NBRP);

  // ---- TAG branch: Hb=S0, M1=S1, M2=S2, HN=S3 ----
  gm6_kernel<<<Bg, 512, 0, stream>>>(XF, NBRG, M16);
  gm6_kernel<<<Bg, 512, 0, stream>>>(M16, NBRG, M26);
  proj3_kernel<<<2048, 128, 0, stream>>>(XF, M16, M26, tag1_W, tag1_b, S0, 6, 0, 0, FLAG);
  pool_kernel<<<Bg, 512, 0, stream>>>(S0, Z, 0, 128);

  gm128_kernel<<<Bg * Nn, 128, 0, stream>>>(S0, NBRG, S1);
  gm128_kernel<<<Bg * Nn, 128, 0, stream>>>(S1, NBRG, S2);
  proj3_kernel<<<2048, 128, 0, stream>>>(S0, S1, S2, tag_W, tag_b, S3, 128, 0, 0, FLAG);
  pool_kernel<<<Bg, 512, 0, stream>>>(S3, Z, 256, 384);

  gm128_kernel<<<Bg * Nn, 128, 0, stream>>>(S3, NBRG, S1);
  gm128_kernel<<<Bg * Nn, 128, 0, stream>>>(S1, NBRG, S2);
  proj3_kernel<<<2048, 128, 0, stream>>>(S3, S1, S2, tag_W, tag_b, S0, 128,
                                         3L * 128 * 128, 128, FLAG);
  pool_kernel<<<Bg, 512, 0, stream>>>(S0, Z, 512, 640);

  // ---- point branch: U=S0, V=S1; Y rotates S2/S3; G uses S0+S1 (16 MB) ----
  proj_dual_kernel<<<2048, 128, 0, stream>>>(XF, p1_W1, S0, S1, 6, 0, FLAG);
  edge_mlp1_kernel<<<2048, 128, 0, stream>>>(S0, S1, NBRP, p1_W2, p1_b1, p1_b2, S2, FLAG);  // Y0=S2
  pool_kernel<<<Bg, 512, 0, stream>>>(S2, Z, 768, 1152);

  for (int c = 0; c < Bg; c += GC16) {             // G=S0+S1 (U,V dead)
    gram_kernel<<<GC16 * 64, 256, 0, stream>>>(S2, S0, c);
    knn3_gram_kernel<<<GC16 * Nn / 4, 256, 0, stream>>>(S0, NBRP, c);
  }
  proj_dual_kernel<<<2048, 128, 0, stream>>>(S2, pf_W, S0, S1, 128, 0, FLAG);  // G dead
  edge_max_kernel<<<Bg * Nn, 128, 0, stream>>>(S0, S1, NBRP, pf_b, S3, 0, FLAG);  // Y1=S3
  pool_kernel<<<Bg, 512, 0, stream>>>(S3, Z, 896, 1280);

  for (int c = 0; c < Bg; c += GC16) {             // G=S0+S1 (U,V dead)
    gram_kernel<<<GC16 * 64, 256, 0, stream>>>(S3, S0, c);
    knn3_gram_kernel<<<GC16 * Nn / 4, 256, 0, stream>>>(S0, NBRP, c);
  }
  proj_dual_kernel<<<2048, 128, 0, stream>>>(S3, pf_W, S0, S1, 128, 256L * 128, FLAG);  // G dead
  edge_max_kernel<<<Bg * Nn, 128, 0, stream>>>(S0, S1, NBRP, pf_b, S2, 128, FLAG);  // Y2=S2 (Y0 dead)
  pool_kernel<<<Bg, 512, 0, stream>>>(S2, Z, 1024, 1408);

  // ---- head ----
  bn_kernel<<<6, 256, 0, stream>>>(Z, bn_g, bn_b, FLAG);
  hl_kernel<<<192, 256, 0, stream>>>(Z, lin_W, lin_b, ZB, 0L, 0L, FLAG);
  hl_kernel<<<192, 256, 0, stream>>>(ZB, lin_W, lin_b, Z, 1L * DIM2 * DIM2, 1L * DIM2, FLAG);
  hl_kernel<<<192, 256, 0, stream>>>(Z, lin_W, lin_b, ZB, 2L * DIM2 * DIM2, 2L * DIM2, FLAG);
  hl_kernel<<<192, 256, 0, stream>>>(ZB, lin_W, lin_b, Z, 3L * DIM2 * DIM2, 3L * DIM2, FLAG);
  hl_kernel<<<192, 256, 0, stream>>>(Z, lin_W, lin_b, ZB, 4L * DIM2 * DIM2, 4L * DIM2, FLAG);
  final_kernel<<<Bg, 256, 0, stream>>>(ZB, out_W, out_b, d_out, FLAG);
}

// Round 6
// 1460.298 us; speedup vs baseline: 1.4522x; 1.2136x over previous
//
#include <hip/hip_runtime.h>
#include <hip/hip_bf16.h>

#define Bg 32
#define Nn 512
#define Fdim 6
#define Wd 128
#define KG 100
#define KP 3
#define DIM2 1536
#define GC16 16

typedef __hip_bfloat16 bf16;
typedef unsigned long long ull;

__device__ __forceinline__ float b2f(bf16 v) { return __bfloat162float(v); }
__device__ __forceinline__ float lrelu(float v) { return v > 0.0f ? v : 0.01f * v; }

// ---------- dtype detection (f32=1 / bf16=0), from low-half u16 bit patterns ----------
__global__ void detect_kernel(const unsigned short* __restrict__ x, int* __restrict__ flag) {
  if (threadIdx.x == 0 && blockIdx.x == 0) {
    int big = 0;
    for (int i = 0; i < 512; i += 2) {
      unsigned short u = x[i];
      int e = (u >> 7) & 0xFF;
      if (e >= 140) big++;
    }
    *flag = (big > 20) ? 1 : 0;
  }
}

// ---------- convert x -> f32 ----------
__global__ void convert_kernel(const void* __restrict__ x, float* __restrict__ xf, int n,
                               const int* __restrict__ flag) {
  int i = blockIdx.x * 256 + threadIdx.x;
  if (i >= n) return;
  if (*flag) xf[i] = ((const float*)x)[i];
  else       xf[i] = b2f(((const bf16*)x)[i]);
}

// ---------- branchless sorted-3 insert (k0<=k1<=k2 kept smallest) ----------
__device__ __forceinline__ void ins3b(ull key, ull& k0, ull& k1, ull& k2) {
  ull M0 = k0 < key ? key : k0;  k0 = k0 < key ? k0 : key;
  ull M1 = k1 < M0 ? M0 : k1;    k1 = k1 < M0 ? k1 : M0;
  k2 = k2 < M1 ? k2 : M1;
}

// ---------- kNN k=100: one wave/row; ballot-popcount radix search (no permutes) ----------
__global__ void knn100_kernel(const float* __restrict__ xf, int* __restrict__ nbr) {
  __shared__ float xg[Nn * 7];   // stride-7: 2-way banks only
  __shared__ float sqv[Nn];
  int t = threadIdx.x; int w = t >> 6; int l = t & 63;
  int row0 = blockIdx.x * 4; int g = row0 >> 9;   // 4 rows (one per wave) per block
  const float* xp = xf + g * (Nn * Fdim);
  for (int j = t; j < Nn; j += 256) {
    float s = 0.0f;
    #pragma unroll
    for (int c = 0; c < Fdim; c++) { float v = xp[j * Fdim + c]; xg[j * 7 + c] = v; s += v * v; }
    sqv[j] = s;
  }
  __syncthreads();
  int i = (row0 & 511) + w;
  float xi[Fdim];
  #pragma unroll
  for (int c = 0; c < Fdim; c++) xi[c] = xg[i * 7 + c];
  float sqi = sqv[i];
  unsigned m[8];
  #pragma unroll
  for (int ch = 0; ch < 8; ch++) {
    int j = ch * 64 + l;
    float dot = 0.0f;
    #pragma unroll
    for (int c = 0; c < Fdim; c++) dot += xi[c] * xg[j * 7 + c];
    float d = sqi + sqv[j] - 2.0f * dot;
    if (j == i) d += 1e10f;
    unsigned u = __float_as_uint(d);
    m[ch] = (u & 0x80000000u) ? ~u : (u | 0x80000000u);
  }
  // binary search for T = exact 100th-smallest key; count via ballot+popcount
  unsigned T = 0u;
  for (int b = 31; b >= 0; b--) {
    unsigned mid = T | (1u << b);
    int c = 0;
    #pragma unroll
    for (int ch = 0; ch < 8; ch++) c += __popcll(__ballot(m[ch] < mid));
    if (c < KG) T = mid;
  }
  int* outp = nbr + ((size_t)(g * Nn + i)) * KG;
  ull lmask = (1ull << l) - 1ull;
  int base = 0;
  #pragma unroll
  for (int ch = 0; ch < 8; ch++) {
    bool less = m[ch] < T;
    ull bal = __ballot(less);
    if (less) outp[base + __popcll(bal & lmask)] = ch * 64 + l;
    base += __popcll(bal);
  }
  int need = KG - base;   // fill remainder with m == T, smallest idx first (stable top_k)
  int eqb = 0;
  #pragma unroll
  for (int ch = 0; ch < 8; ch++) {
    bool eq = (m[ch] == T);
    ull bal = __ballot(eq);
    int gr = eqb + __popcll(bal & lmask);
    if (eq && gr < need) outp[base + gr] = ch * 64 + l;
    eqb += __popcll(bal);
  }
}

// ---------- kNN k=3 on coords: 16 lanes/row, serial scan + 4-step butterfly ----------
__global__ void knn3_x_kernel(const float* __restrict__ xf, int* __restrict__ nbr) {
  __shared__ float xg[Nn * 7];
  __shared__ float sqv[Nn];
  int t = threadIdx.x; int bid = blockIdx.x;   // 1024 blocks, 16 rows/block
  int g = bid >> 5;
  const float* xp = xf + g * (Nn * Fdim);
  for (int j = t; j < Nn; j += 256) {
    float s = 0.0f;
    #pragma unroll
    for (int c = 0; c < Fdim; c++) { float v = xp[j * Fdim + c]; xg[j * 7 + c] = v; s += v * v; }
    sqv[j] = s;
  }
  __syncthreads();
  int lr = t >> 4;           // local row 0..15
  int sub = t & 15;          // sub-lane within row
  int l = t & 63;
  int i = ((bid & 31) << 4) + lr;
  float xi[Fdim];
  #pragma unroll
  for (int c = 0; c < Fdim; c++) xi[c] = xg[i * 7 + c];
  float sqi = sqv[i];
  ull k0 = ~0ull, k1 = ~0ull, k2 = ~0ull;
  for (int jj = 0; jj < 32; jj++) {
    int s = (jj + l) & 31;          // rotation: conflict-free banks, same set
    int j = sub * 32 + s;
    float dot = 0.0f;
    #pragma unroll
    for (int c = 0; c < Fdim; c++) dot += xi[c] * xg[j * 7 + c];
    float d = sqi + sqv[j] - 2.0f * dot;
    if (j == i) d += 1e10f;
    unsigned u = __float_as_uint(d);
    unsigned m = (u & 0x80000000u) ? ~u : (u | 0x80000000u);
    ins3b(((ull)m << 32) | (unsigned)j, k0, k1, k2);
  }
  #pragma unroll
  for (int off = 1; off <= 8; off <<= 1) {
    ull b0 = __shfl_xor(k0, off, 64);
    ull b1 = __shfl_xor(k1, off, 64);
    ull b2 = __shfl_xor(k2, off, 64);
    ins3b(b0, k0, k1, k2); ins3b(b1, k0, k1, k2); ins3b(b2, k0, k1, k2);
  }
  if (sub == 0) {
    int row = g * Nn + i;
    nbr[row * 3 + 0] = (int)(k0 & 0xFFFFFFFFu);
    nbr[row * 3 + 1] = (int)(k1 & 0xFFFFFFFFu);
    nbr[row * 3 + 2] = (int)(k2 & 0xFFFFFFFFu);
  }
}

// ---------- kNN k=3 from chunked Gram: 16 lanes/row, sq norms from G diagonal ----------
__global__ void knn3_gram_kernel(const float* __restrict__ G, int* __restrict__ nbr, int g0) {
  __shared__ float sqv[Nn];
  int t = threadIdx.x; int bid = blockIdx.x;   // 512 blocks/launch, 16 rows/block
  int gl = bid >> 5; int g = g0 + gl;
  const float* Gg = G + (size_t)gl * Nn * Nn;
  for (int j = t; j < Nn; j += 256) sqv[j] = Gg[(size_t)j * Nn + j];
  __syncthreads();
  int lr = t >> 4; int sub = t & 15; int l = t & 63;
  int i = ((bid & 31) << 4) + lr;
  float sqi = sqv[i];
  const float* Gr = Gg + (size_t)i * Nn;
  ull k0 = ~0ull, k1 = ~0ull, k2 = ~0ull;
  for (int jj = 0; jj < 32; jj++) {
    int s = (jj + l) & 31;
    int j = sub * 32 + s;
    float d = sqi + sqv[j] - 2.0f * Gr[j];
    if (j == i) d += 1e10f;
    unsigned u = __float_as_uint(d);
    unsigned m = (u & 0x80000000u) ? ~u : (u | 0x80000000u);
    ins3b(((ull)m << 32) | (unsigned)j, k0, k1, k2);
  }
  #pragma unroll
  for (int off = 1; off <= 8; off <<= 1) {
    ull b0 = __shfl_xor(k0, off, 64);
    ull b1 = __shfl_xor(k1, off, 64);
    ull b2 = __shfl_xor(k2, off, 64);
    ins3b(b0, k0, k1, k2); ins3b(b1, k0, k1, k2); ins3b(b2, k0, k1, k2);
  }
  if (sub == 0) {
    int row = g * Nn + i;
    nbr[row * 3 + 0] = (int)(k0 & 0xFFFFFFFFu);
    nbr[row * 3 + 1] = (int)(k1 & 0xFFFFFFFFu);
    nbr[row * 3 + 2] = (int)(k2 & 0xFFFFFFFFu);
  }
}

// ---------- neighbor-mean over 100, C=6 ----------
__global__ void gm6_kernel(const float* __restrict__ src, const int* __restrict__ nbr,
                           float* __restrict__ dst) {
  __shared__ float s[Nn * Fdim];
  int g = blockIdx.x; int t = threadIdx.x;  // 512
  const float* sp = src + g * (Nn * Fdim);
  for (int idx = t; idx < Nn * Fdim; idx += 512) s[idx] = sp[idx];
  __syncthreads();
  float acc[Fdim] = {0, 0, 0, 0, 0, 0};
  const int* nb = nbr + ((size_t)(g * Nn + t)) * KG;
  for (int k = 0; k < KG; k++) {
    int j = nb[k];
    #pragma unroll
    for (int c = 0; c < Fdim; c++) acc[c] += s[j * Fdim + c];
  }
  float* dp = dst + (size_t)(g * Nn + t) * Fdim;
  #pragma unroll
  for (int c = 0; c < Fdim; c++) dp[c] = acc[c] / 100.0f;
}

// ---------- neighbor-mean over 100, C=128 ----------
__global__ void gm128_kernel(const float* __restrict__ src, const int* __restrict__ nbr,
                             float* __restrict__ dst) {
  __shared__ int ids[KG];
  int row = blockIdx.x; int g = row >> 9; int t = threadIdx.x;  // 128
  if (t < KG) ids[t] = nbr[(size_t)row * KG + t];
  __syncthreads();
  const float* sp = src + (size_t)g * Nn * Wd;
  float acc = 0.0f;
  #pragma unroll 4
  for (int k = 0; k < KG; k++) acc += sp[ids[k] * Wd + t];
  dst[(size_t)row * Wd + t] = acc / 100.0f;
}

// ---------- out = lrelu(in0@W[0] + in1@W[1] + in2@W[2] + b) ----------
__global__ void proj3_kernel(const float* __restrict__ in0, const float* __restrict__ in1,
                             const float* __restrict__ in2, const void* __restrict__ Wt_,
                             const void* __restrict__ bt_, float* __restrict__ out, int C,
                             long Woff, long boff, const int* __restrict__ flag) {
  __shared__ float s0[8 * 128], s1[8 * 128], s2[8 * 128];
  int t = threadIdx.x;  // 128
  int node0 = blockIdx.x * 8;
  int f32 = *flag;
  int nC = 8 * C;
  for (int idx = t; idx < nC; idx += 128) {
    s0[idx] = in0[(size_t)node0 * C + idx];
    s1[idx] = in1[(size_t)node0 * C + idx];
    s2[idx] = in2[(size_t)node0 * C + idx];
  }
  __syncthreads();
  float acc[8] = {0, 0, 0, 0, 0, 0, 0, 0};
  float bd;
  if (f32) {
    const float* W = (const float*)Wt_ + Woff;
    for (int c = 0; c < C; c++) {
      float w0 = W[c * 128 + t], w1 = W[(C + c) * 128 + t], w2 = W[(2 * C + c) * 128 + t];
      #pragma unroll
      for (int n = 0; n < 8; n++)
        acc[n] += s0[n * C + c] * w0 + s1[n * C + c] * w1 + s2[n * C + c] * w2;
    }
    bd = ((const float*)bt_ + boff)[t];
  } else {
    const bf16* W = (const bf16*)Wt_ + Woff;
    for (int c = 0; c < C; c++) {
      float w0 = b2f(W[c * 128 + t]), w1 = b2f(W[(C + c) * 128 + t]), w2 = b2f(W[(2 * C + c) * 128 + t]);
      #pragma unroll
      for (int n = 0; n < 8; n++)
        acc[n] += s0[n * C + c] * w0 + s1[n * C + c] * w1 + s2[n * C + c] * w2;
    }
    bd = b2f(((const bf16*)bt_ + boff)[t]);
  }
  #pragma unroll
  for (int n = 0; n < 8; n++)
    out[(size_t)(node0 + n) * 128 + t] = lrelu(acc[n] + bd);
}

// ---------- u = in@W[0:C], v = in@W[C:2C] ----------
__global__ void proj_dual_kernel(const float* __restrict__ in, const void* __restrict__ Wt_,
                                 float* __restrict__ u, float* __restrict__ v, int C,
                                 long Woff, const int* __restrict__ flag) {
  __shared__ float s0[8 * 128];
  int t = threadIdx.x; int node0 = blockIdx.x * 8;
  int f32 = *flag;
  for (int idx = t; idx < 8 * C; idx += 128) s0[idx] = in[(size_t)node0 * C + idx];
  __syncthreads();
  float au[8] = {0, 0, 0, 0, 0, 0, 0, 0};
  float av[8] = {0, 0, 0, 0, 0, 0, 0, 0};
  if (f32) {
    const float* W = (const float*)Wt_ + Woff;
    for (int c = 0; c < C; c++) {
      float wa = W[c * 128 + t], wb = W[(C + c) * 128 + t];
      #pragma unroll
      for (int n = 0; n < 8; n++) { float x = s0[n * C + c]; au[n] += x * wa; av[n] += x * wb; }
    }
  } else {
    const bf16* W = (const bf16*)Wt_ + Woff;
    for (int c = 0; c < C; c++) {
      float wa = b2f(W[c * 128 + t]), wb = b2f(W[(C + c) * 128 + t]);
      #pragma unroll
      for (int n = 0; n < 8; n++) { float x = s0[n * C + c]; au[n] += x * wa; av[n] += x * wb; }
    }
  }
  #pragma unroll
  for (int n = 0; n < 8; n++) {
    u[(size_t)(node0 + n) * 128 + t] = au[n];
    v[(size_t)(node0 + n) * 128 + t] = av[n];
  }
}

// ---------- edgeconv1 ----------
__global__ void edge_mlp1_kernel(const float* __restrict__ u, const float* __restrict__ v,
                                 const int* __restrict__ nbrp, const void* __restrict__ W2_,
                                 const void* __restrict__ b1_, const void* __restrict__ b2_,
                                 float* __restrict__ y, const int* __restrict__ flag) {
  __shared__ float tl[8][3][128];
  int t = threadIdx.x; int node0 = blockIdx.x * 8; int g = node0 >> 9;
  int f32 = *flag;
  float b1d;
  if (f32) b1d = ((const float*)b1_)[t]; else b1d = b2f(((const bf16*)b1_)[t]);
  for (int n = 0; n < 8; n++) {
    int row = node0 + n;
    float ui = u[(size_t)row * 128 + t], vi = v[(size_t)row * 128 + t];
    #pragma unroll
    for (int k = 0; k < 3; k++) {
      int j = nbrp[row * 3 + k];
      tl[n][k][t] = lrelu(ui + v[(size_t)(g * Nn + j) * 128 + t] - vi + b1d);
    }
  }
  __syncthreads();
  float acc[8][3];
  #pragma unroll
  for (int n = 0; n < 8; n++)
    #pragma unroll
    for (int k = 0; k < 3; k++) acc[n][k] = 0.0f;
  if (f32) {
    const float* W = (const float*)W2_;
    for (int c = 0; c < 128; c++) {
      float w = W[c * 128 + t];
      #pragma unroll
      for (int n = 0; n < 8; n++)
        #pragma unroll
        for (int k = 0; k < 3; k++) acc[n][k] += tl[n][k][c] * w;
    }
  } else {
    const bf16* W = (const bf16*)W2_;
    for (int c = 0; c < 128; c++) {
      float w = b2f(W[c * 128 + t]);
      #pragma unroll
      for (int n = 0; n < 8; n++)
        #pragma unroll
        for (int k = 0; k < 3; k++) acc[n][k] += tl[n][k][c] * w;
    }
  }
  float b2d;
  if (f32) b2d = ((const float*)b2_)[t]; else b2d = b2f(((const bf16*)b2_)[t]);
  #pragma unroll
  for (int n = 0; n < 8; n++) {
    float m = lrelu(acc[n][0] + b2d);
    m = fmaxf(m, lrelu(acc[n][1] + b2d));
    m = fmaxf(m, lrelu(acc[n][2] + b2d));
    y[(size_t)(node0 + n) * 128 + t] = m;
  }
}

// ---------- edgeconv2/3 ----------
__global__ void edge_max_kernel(const float* __restrict__ u, const float* __restrict__ v,
                                const int* __restrict__ nbrp, const void* __restrict__ bias_,
                                float* __restrict__ y, long boff, const int* __restrict__ flag) {
  int row = blockIdx.x; int g = row >> 9; int t = threadIdx.x;  // 128
  float ui = u[(size_t)row * 128 + t], vi = v[(size_t)row * 128 + t];
  float bd;
  if (*flag) bd = ((const float*)bias_ + boff)[t]; else bd = b2f(((const bf16*)bias_ + boff)[t]);
  float m = -3.4e38f;
  #pragma unroll
  for (int k = 0; k < 3; k++) {
    int j = nbrp[row * 3 + k];
    m = fmaxf(m, lrelu(ui - vi + v[(size_t)(g * Nn + j) * 128 + t] + bd));
  }
  y[(size_t)row * 128 + t] = m;
}

// ---------- chunked Gram matrix: G[gl] = Y[g0+gl] Y[g0+gl]^T ----------
__global__ void gram_kernel(const float* __restrict__ y, float* __restrict__ G, int g0) {
  __shared__ float As[64][17], Bs[64][17];
  int bid = blockIdx.x;
  int gl = bid >> 6; int tt = bid & 63; int ti = tt >> 3; int tj = tt & 7;
  int g = g0 + gl;
  int t = threadIdx.x; int tx = t & 15, ty = t >> 4;
  const float* Yg = y + (size_t)g * Nn * Wd;
  float* Gg = G + (size_t)gl * Nn * Nn;
  float c[4][4];
  #pragma unroll
  for (int p = 0; p < 4; p++)
    #pragma unroll
    for (int q = 0; q < 4; q++) c[p][q] = 0.0f;
  for (int k0 = 0; k0 < 128; k0 += 16) {
    for (int idx = t; idx < 1024; idx += 256) {
      int r = idx >> 4, cc = idx & 15;
      As[r][cc] = Yg[(ti * 64 + r) * 128 + k0 + cc];
      Bs[r][cc] = Yg[(tj * 64 + r) * 128 + k0 + cc];
    }
    __syncthreads();
    for (int kk = 0; kk < 16; kk++) {
      float a[4], bb[4];
      #pragma unroll
      for (int p = 0; p < 4; p++) a[p] = As[ty * 4 + p][kk];
      #pragma unroll
      for (int q = 0; q < 4; q++) bb[q] = Bs[tx * 4 + q][kk];
      #pragma unroll
      for (int p = 0; p < 4; p++)
        #pragma unroll
        for (int q = 0; q < 4; q++) c[p][q] += a[p] * bb[q];
    }
    __syncthreads();
  }
  #pragma unroll
  for (int p = 0; p < 4; p++)
    #pragma unroll
    for (int q = 0; q < 4; q++)
      Gg[(size_t)(ti * 64 + ty * 4 + p) * Nn + tj * 64 + tx * 4 + q] = c[p][q];
}

// ---------- mean+max pool ----------
__global__ void pool_kernel(const float* __restrict__ h, float* __restrict__ z,
                            int meanoff, int maxoff) {
  __shared__ float sm[4][128], sx[4][128];
  int g = blockIdx.x; int t = threadIdx.x;  // 512
  int c = t & 127, q = t >> 7;
  const float* hg = h + (size_t)g * Nn * Wd;
  float s = 0.0f, m = -3.4e38f;
  for (int n = q * 128; n < q * 128 + 128; n++) {
    float vv = hg[n * 128 + c];
    s += vv; m = fmaxf(m, vv);
  }
  sm[q][c] = s; sx[q][c] = m;
  __syncthreads();
  if (q == 0) {
    s = sm[0][c] + sm[1][c] + sm[2][c] + sm[3][c];
    m = fmaxf(fmaxf(sx[0][c], sx[1][c]), fmaxf(sx[2][c], sx[3][c]));
    z[g * DIM2 + meanoff + c] = s / 512.0f;
    z[g * DIM2 + maxoff + c] = m;
  }
}

// ---------- BatchNorm1d (batch stats), in place ----------
__global__ void bn_kernel(float* __restrict__ z, const void* __restrict__ gamma,
                          const void* __restrict__ beta, const int* __restrict__ flag) {
  int c = blockIdx.x * 256 + threadIdx.x;
  if (c >= DIM2) return;
  float s = 0.0f;
  for (int r = 0; r < Bg; r++) s += z[r * DIM2 + c];
  float mu = s / 32.0f;
  float v = 0.0f;
  for (int r = 0; r < Bg; r++) { float d = z[r * DIM2 + c] - mu; v += d * d; }
  float var = v / 32.0f;
  float gm, bt;
  if (*flag) { gm = ((const float*)gamma)[c]; bt = ((const float*)beta)[c]; }
  else       { gm = b2f(((const bf16*)gamma)[c]); bt = b2f(((const bf16*)beta)[c]); }
  float scale = gm / sqrtf(var + 1e-5f);
  for (int r = 0; r < Bg; r++) z[r * DIM2 + c] = (z[r * DIM2 + c] - mu) * scale + bt;
}

// ---------- head linear ----------
__global__ void hl_kernel(const float* __restrict__ in, const void* __restrict__ Wt_,
                          const void* __restrict__ bt_, float* __restrict__ out,
                          long Woff, long boff, const int* __restrict__ flag) {
  __shared__ float a[32 * 129];
  int t = threadIdx.x; int dcol = blockIdx.x * 8 + (t >> 5); int r = t & 31;
  int f32 = *flag;
  float acc = 0.0f;
  for (int k0 = 0; k0 < DIM2; k0 += 128) {
    for (int idx = t; idx < 4096; idx += 256) {
      int rr = idx >> 7, kk = idx & 127;
      a[rr * 129 + kk] = in[rr * DIM2 + k0 + kk];
    }
    __syncthreads();
    if (f32) {
      const float* W = (const float*)Wt_ + Woff;
      for (int kk = 0; kk < 128; kk++)
        acc += a[r * 129 + kk] * W[(size_t)(k0 + kk) * DIM2 + dcol];
    } else {
      const bf16* W = (const bf16*)Wt_ + Woff;
      for (int kk = 0; kk < 128; kk++)
        acc += a[r * 129 + kk] * b2f(W[(size_t)(k0 + kk) * DIM2 + dcol]);
    }
    __syncthreads();
  }
  float bd;
  if (f32) bd = ((const float*)bt_ + boff)[dcol]; else bd = b2f(((const bf16*)bt_ + boff)[dcol]);
  out[r * DIM2 + dcol] = lrelu(acc + bd);
}

// ---------- final ----------
__global__ void final_kernel(const float* __restrict__ zin, const void* __restrict__ outW,
                             const void* __restrict__ outb, void* __restrict__ out,
                             const int* __restrict__ flag) {
  __shared__ float red[256];
  int r = blockIdx.x, t = threadIdx.x;
  int f32 = *flag;
  float acc = 0.0f;
  if (f32) {
    const float* W = (const float*)outW;
    for (int c = t; c < DIM2; c += 256) acc += zin[r * DIM2 + c] * W[c];
  } else {
    const bf16* W = (const bf16*)outW;
    for (int c = t; c < DIM2; c += 256) acc += zin[r * DIM2 + c] * b2f(W[c]);
  }
  red[t] = acc; __syncthreads();
  for (int s = 128; s > 0; s >>= 1) { if (t < s) red[t] += red[t + s]; __syncthreads(); }
  if (t == 0) {
    float ob;
    if (f32) ob = ((const float*)outb)[0]; else ob = b2f(((const bf16*)outb)[0]);
    float val = red[0] + ob;
    if (f32) ((float*)out)[r] = val;
    else     ((bf16*)out)[r] = __float2bfloat16(val);
  }
}

extern "C" void kernel_launch(void* const* d_in, const int* in_sizes, int n_in,
                              void* d_out, int out_size, void* d_ws, size_t ws_size,
                              hipStream_t stream) {
  const void* x      = d_in[0];
  const void* tag1_W = d_in[2];
  const void* tag1_b = d_in[3];
  const void* tag_W  = d_in[4];
  const void* tag_b  = d_in[5];
  const void* p1_W1  = d_in[6];
  const void* p1_b1  = d_in[7];
  const void* p1_W2  = d_in[8];
  const void* p1_b2  = d_in[9];
  const void* pf_W   = d_in[10];
  const void* pf_b   = d_in[11];
  const void* bn_g   = d_in[12];
  const void* bn_b   = d_in[13];
  const void* lin_W  = d_in[14];
  const void* lin_b  = d_in[15];
  const void* out_W  = d_in[16];
  const void* out_b  = d_in[17];

  // ---- workspace layout: total 10,485,776 floats ≈ 40 MB ----
  float* ws = (float*)d_ws;
  float* XF   = ws + 0;                 // 98304
  float* M16  = ws + 98304;             // 98304
  float* M26  = ws + 196608;            // 98304
  float* Z    = ws + 294912;            // 49152
  float* ZB   = ws + 344064;            // 49152
  int*   FLAG = (int*)(ws + 409600);    // 16
  int*   NBRP = (int*)(ws + 409616);    // 49152 ints
  int*   NBRG = (int*)(ws + 458768);    // 1,638,400 ints -> ends 2,097,168
  float* S0   = ws + 2097168;           // 4 slots x 2,097,152 floats (8 MB each)
  float* S1   = ws + 4194320;           // S0+S1 contiguous -> 16 MB G region
  float* S2   = ws + 6291472;
  float* S3   = ws + 8388624;           // ends 10,485,776 floats

  detect_kernel<<<1, 64, 0, stream>>>((const unsigned short*)x, FLAG);
  convert_kernel<<<384, 256, 0, stream>>>(x, XF, Bg * Nn * Fdim, FLAG);
  knn100_kernel<<<Bg * Nn / 4, 256, 0, stream>>>(XF, NBRG);
  knn3_x_kernel<<<Bg * Nn / 16, 256, 0, stream>>>(XF, NBRP);

  // ---- TAG branch: Hb=S0, M1=S1, M2=S2, HN=S3 ----
  gm6_kernel<<<Bg, 512, 0, stream>>>(XF, NBRG, M16);
  gm6_kernel<<<Bg, 512, 0, stream>>>(M16, NBRG, M26);
  proj3_kernel<<<2048, 128, 0, stream>>>(XF, M16, M26, tag1_W, tag1_b, S0, 6, 0, 0, FLAG);
  pool_kernel<<<Bg, 512, 0, stream>>>(S0, Z, 0, 128);

  gm128_kernel<<<Bg * Nn, 128, 0, stream>>>(S0, NBRG, S1);
  gm128_kernel<<<Bg * Nn, 128, 0, stream>>>(S1, NBRG, S2);
  proj3_kernel<<<2048, 128, 0, stream>>>(S0, S1, S2, tag_W, tag_b, S3, 128, 0, 0, FLAG);
  pool_kernel<<<Bg, 512, 0, stream>>>(S3, Z, 256, 384);

  gm128_kernel<<<Bg * Nn, 128, 0, stream>>>(S3, NBRG, S1);
  gm128_kernel<<<Bg * Nn, 128, 0, stream>>>(S1, NBRG, S2);
  proj3_kernel<<<2048, 128, 0, stream>>>(S3, S1, S2, tag_W, tag_b, S0, 128,
                                         3L * 128 * 128, 128, FLAG);
  pool_kernel<<<Bg, 512, 0, stream>>>(S0, Z, 512, 640);

  // ---- point branch: U=S0, V=S1; Y rotates S2/S3; G uses S0+S1 (16 MB) ----
  proj_dual_kernel<<<2048, 128, 0, stream>>>(XF, p1_W1, S0, S1, 6, 0, FLAG);
  edge_mlp1_kernel<<<2048, 128, 0, stream>>>(S0, S1, NBRP, p1_W2, p1_b1, p1_b2, S2, FLAG);  // Y0=S2
  pool_kernel<<<Bg, 512, 0, stream>>>(S2, Z, 768, 1152);

  for (int c = 0; c < Bg; c += GC16) {             // G=S0+S1 (U,V dead)
    gram_kernel<<<GC16 * 64, 256, 0, stream>>>(S2, S0, c);
    knn3_gram_kernel<<<GC16 * Nn / 16, 256, 0, stream>>>(S0, NBRP, c);
  }
  proj_dual_kernel<<<2048, 128, 0, stream>>>(S2, pf_W, S0, S1, 128, 0, FLAG);  // G dead
  edge_max_kernel<<<Bg * Nn, 128, 0, stream>>>(S0, S1, NBRP, pf_b, S3, 0, FLAG);  // Y1=S3
  pool_kernel<<<Bg, 512, 0, stream>>>(S3, Z, 896, 1280);

  for (int c = 0; c < Bg; c += GC16) {             // G=S0+S1 (U,V dead)
    gram_kernel<<<GC16 * 64, 256, 0, stream>>>(S3, S0, c);
    knn3_gram_kernel<<<GC16 * Nn / 16, 256, 0, stream>>>(S0, NBRP, c);
  }
  proj_dual_kernel<<<2048, 128, 0, stream>>>(S3, pf_W, S0, S1, 128, 256L * 128, FLAG);  // G dead
  edge_max_kernel<<<Bg * Nn, 128, 0, stream>>>(S0, S1, NBRP, pf_b, S2, 128, FLAG);  // Y2=S2 (Y0 dead)
  pool_kernel<<<Bg, 512, 0, stream>>>(S2, Z, 1024, 1408);

  // ---- head ----
  bn_kernel<<<6, 256, 0, stream>>>(Z, bn_g, bn_b, FLAG);
  hl_kernel<<<192, 256, 0, stream>>>(Z, lin_W, lin_b, ZB, 0L, 0L, FLAG);
  hl_kernel<<<192, 256, 0, stream>>>(ZB, lin_W, lin_b, Z, 1L * DIM2 * DIM2, 1L * DIM2, FLAG);
  hl_kernel<<<192, 256, 0, stream>>>(Z, lin_W, lin_b, ZB, 2L * DIM2 * DIM2, 2L * DIM2, FLAG);
  hl_kernel<<<192, 256, 0, stream>>>(ZB, lin_W, lin_b, Z, 3L * DIM2 * DIM2, 3L * DIM2, FLAG);
  hl_kernel<<<192, 256, 0, stream>>>(Z, lin_W, lin_b, ZB, 4L * DIM2 * DIM2, 4L * DIM2, FLAG);
  final_kernel<<<Bg, 256, 0, stream>>>(ZB, out_W, out_b, d_out, FLAG);
}

// Round 8
// 1315.240 us; speedup vs baseline: 1.6124x; 1.1103x over previous
//
#include <hip/hip_runtime.h>
#include <hip/hip_bf16.h>

#define Bg 32
#define Nn 512
#define Fdim 6
#define Wd 128
#define KG 100
#define KP 3
#define DIM2 1536
#define GC16 16

typedef __hip_bfloat16 bf16;
typedef unsigned long long ull;

__device__ __forceinline__ float b2f(bf16 v) { return __bfloat162float(v); }
__device__ __forceinline__ float lrelu(float v) { return v > 0.0f ? v : 0.01f * v; }

// ---------- dtype detection (f32=1 / bf16=0), from low-half u16 bit patterns ----------
__global__ void detect_kernel(const unsigned short* __restrict__ x, int* __restrict__ flag) {
  if (threadIdx.x == 0 && blockIdx.x == 0) {
    int big = 0;
    for (int i = 0; i < 512; i += 2) {
      unsigned short u = x[i];
      int e = (u >> 7) & 0xFF;
      if (e >= 140) big++;
    }
    *flag = (big > 20) ? 1 : 0;
  }
}

// ---------- convert x -> f32 ----------
__global__ void convert_kernel(const void* __restrict__ x, float* __restrict__ xf, int n,
                               const int* __restrict__ flag) {
  int i = blockIdx.x * 256 + threadIdx.x;
  if (i >= n) return;
  if (*flag) xf[i] = ((const float*)x)[i];
  else       xf[i] = b2f(((const bf16*)x)[i]);
}

// ---------- branchless sorted-3 insert (k0<=k1<=k2 kept smallest) ----------
__device__ __forceinline__ void ins3b(ull key, ull& k0, ull& k1, ull& k2) {
  ull M0 = k0 < key ? key : k0;  k0 = k0 < key ? k0 : key;
  ull M1 = k1 < M0 ? M0 : k1;    k1 = k1 < M0 ? k1 : M0;
  k2 = k2 < M1 ? k2 : M1;
}

// ---------- kNN k=100: one wave/row; ballot-popcount radix search (no permutes) ----------
__global__ void knn100_kernel(const float* __restrict__ xf, int* __restrict__ nbr) {
  __shared__ float xg[Nn * 7];   // stride-7: 2-way banks only
  __shared__ float sqv[Nn];
  int t = threadIdx.x; int w = t >> 6; int l = t & 63;
  int row0 = blockIdx.x * 4; int g = row0 >> 9;   // 4 rows (one per wave) per block
  const float* xp = xf + g * (Nn * Fdim);
  for (int j = t; j < Nn; j += 256) {
    float s = 0.0f;
    #pragma unroll
    for (int c = 0; c < Fdim; c++) { float v = xp[j * Fdim + c]; xg[j * 7 + c] = v; s += v * v; }
    sqv[j] = s;
  }
  __syncthreads();
  int i = (row0 & 511) + w;
  float xi[Fdim];
  #pragma unroll
  for (int c = 0; c < Fdim; c++) xi[c] = xg[i * 7 + c];
  float sqi = sqv[i];
  unsigned m[8];
  #pragma unroll
  for (int ch = 0; ch < 8; ch++) {
    int j = ch * 64 + l;
    float dot = 0.0f;
    #pragma unroll
    for (int c = 0; c < Fdim; c++) dot += xi[c] * xg[j * 7 + c];
    float d = sqi + sqv[j] - 2.0f * dot;
    if (j == i) d += 1e10f;
    unsigned u = __float_as_uint(d);
    m[ch] = (u & 0x80000000u) ? ~u : (u | 0x80000000u);
  }
  // binary search for T = exact 100th-smallest key; count via ballot+popcount
  unsigned T = 0u;
  for (int b = 31; b >= 0; b--) {
    unsigned mid = T | (1u << b);
    int c = 0;
    #pragma unroll
    for (int ch = 0; ch < 8; ch++) c += __popcll(__ballot(m[ch] < mid));
    if (c < KG) T = mid;
  }
  int* outp = nbr + ((size_t)(g * Nn + i)) * KG;
  ull lmask = (1ull << l) - 1ull;
  int base = 0;
  #pragma unroll
  for (int ch = 0; ch < 8; ch++) {
    bool less = m[ch] < T;
    ull bal = __ballot(less);
    if (less) outp[base + __popcll(bal & lmask)] = ch * 64 + l;
    base += __popcll(bal);
  }
  int need = KG - base;   // fill remainder with m == T, smallest idx first (stable top_k)
  int eqb = 0;
  #pragma unroll
  for (int ch = 0; ch < 8; ch++) {
    bool eq = (m[ch] == T);
    ull bal = __ballot(eq);
    int gr = eqb + __popcll(bal & lmask);
    if (eq && gr < need) outp[base + gr] = ch * 64 + l;
    eqb += __popcll(bal);
  }
}

// ---------- kNN k=3 on coords: 16 lanes/row, serial scan + 4-step butterfly ----------
__global__ void knn3_x_kernel(const float* __restrict__ xf, int* __restrict__ nbr) {
  __shared__ float xg[Nn * 7];
  __shared__ float sqv[Nn];
  int t = threadIdx.x; int bid = blockIdx.x;   // 1024 blocks, 16 rows/block
  int g = bid >> 5;
  const float* xp = xf + g * (Nn * Fdim);
  for (int j = t; j < Nn; j += 256) {
    float s = 0.0f;
    #pragma unroll
    for (int c = 0; c < Fdim; c++) { float v = xp[j * Fdim + c]; xg[j * 7 + c] = v; s += v * v; }
    sqv[j] = s;
  }
  __syncthreads();
  int lr = t >> 4;           // local row 0..15
  int sub = t & 15;          // sub-lane within row
  int l = t & 63;
  int i = ((bid & 31) << 4) + lr;
  float xi[Fdim];
  #pragma unroll
  for (int c = 0; c < Fdim; c++) xi[c] = xg[i * 7 + c];
  float sqi = sqv[i];
  ull k0 = ~0ull, k1 = ~0ull, k2 = ~0ull;
  for (int jj = 0; jj < 32; jj++) {
    int s = (jj + l) & 31;          // rotation: conflict-free banks, same set
    int j = sub * 32 + s;
    float dot = 0.0f;
    #pragma unroll
    for (int c = 0; c < Fdim; c++) dot += xi[c] * xg[j * 7 + c];
    float d = sqi + sqv[j] - 2.0f * dot;
    if (j == i) d += 1e10f;
    unsigned u = __float_as_uint(d);
    unsigned m = (u & 0x80000000u) ? ~u : (u | 0x80000000u);
    ins3b(((ull)m << 32) | (unsigned)j, k0, k1, k2);
  }
  #pragma unroll
  for (int off = 1; off <= 8; off <<= 1) {
    ull b0 = __shfl_xor(k0, off, 64);
    ull b1 = __shfl_xor(k1, off, 64);
    ull b2 = __shfl_xor(k2, off, 64);
    ins3b(b0, k0, k1, k2); ins3b(b1, k0, k1, k2); ins3b(b2, k0, k1, k2);
  }
  if (sub == 0) {
    int row = g * Nn + i;
    nbr[row * 3 + 0] = (int)(k0 & 0xFFFFFFFFu);
    nbr[row * 3 + 1] = (int)(k1 & 0xFFFFFFFFu);
    nbr[row * 3 + 2] = (int)(k2 & 0xFFFFFFFFu);
  }
}

// ---------- kNN k=3 from chunked Gram: 16 lanes/row, sq norms from G diagonal ----------
__global__ void knn3_gram_kernel(const float* __restrict__ G, int* __restrict__ nbr, int g0) {
  __shared__ float sqv[Nn];
  int t = threadIdx.x; int bid = blockIdx.x;   // 512 blocks/launch, 16 rows/block
  int gl = bid >> 5; int g = g0 + gl;
  const float* Gg = G + (size_t)gl * Nn * Nn;
  for (int j = t; j < Nn; j += 256) sqv[j] = Gg[(size_t)j * Nn + j];
  __syncthreads();
  int lr = t >> 4; int sub = t & 15; int l = t & 63;
  int i = ((bid & 31) << 4) + lr;
  float sqi = sqv[i];
  const float* Gr = Gg + (size_t)i * Nn;
  ull k0 = ~0ull, k1 = ~0ull, k2 = ~0ull;
  for (int jj = 0; jj < 32; jj++) {
    int s = (jj + l) & 31;
    int j = sub * 32 + s;
    float d = sqi + sqv[j] - 2.0f * Gr[j];
    if (j == i) d += 1e10f;
    unsigned u = __float_as_uint(d);
    unsigned m = (u & 0x80000000u) ? ~u : (u | 0x80000000u);
    ins3b(((ull)m << 32) | (unsigned)j, k0, k1, k2);
  }
  #pragma unroll
  for (int off = 1; off <= 8; off <<= 1) {
    ull b0 = __shfl_xor(k0, off, 64);
    ull b1 = __shfl_xor(k1, off, 64);
    ull b2 = __shfl_xor(k2, off, 64);
    ins3b(b0, k0, k1, k2); ins3b(b1, k0, k1, k2); ins3b(b2, k0, k1, k2);
  }
  if (sub == 0) {
    int row = g * Nn + i;
    nbr[row * 3 + 0] = (int)(k0 & 0xFFFFFFFFu);
    nbr[row * 3 + 1] = (int)(k1 & 0xFFFFFFFFu);
    nbr[row * 3 + 2] = (int)(k2 & 0xFFFFFFFFu);
  }
}

// ---------- neighbor-mean over 100, C=6 ----------
__global__ void gm6_kernel(const float* __restrict__ src, const int* __restrict__ nbr,
                           float* __restrict__ dst) {
  __shared__ float s[Nn * Fdim];
  int g = blockIdx.x; int t = threadIdx.x;  // 512
  const float* sp = src + g * (Nn * Fdim);
  for (int idx = t; idx < Nn * Fdim; idx += 512) s[idx] = sp[idx];
  __syncthreads();
  float acc[Fdim] = {0, 0, 0, 0, 0, 0};
  const int* nb = nbr + ((size_t)(g * Nn + t)) * KG;
  for (int k = 0; k < KG; k++) {
    int j = nb[k];
    #pragma unroll
    for (int c = 0; c < Fdim; c++) acc[c] += s[j * Fdim + c];
  }
  float* dp = dst + (size_t)(g * Nn + t) * Fdim;
  #pragma unroll
  for (int c = 0; c < Fdim; c++) dp[c] = acc[c] / 100.0f;
}

// ---------- neighbor-mean over 100, C=128 ----------
__global__ void gm128_kernel(const float* __restrict__ src, const int* __restrict__ nbr,
                             float* __restrict__ dst) {
  __shared__ int ids[KG];
  int row = blockIdx.x; int g = row >> 9; int t = threadIdx.x;  // 128
  if (t < KG) ids[t] = nbr[(size_t)row * KG + t];
  __syncthreads();
  const float* sp = src + (size_t)g * Nn * Wd;
  float acc = 0.0f;
  #pragma unroll 4
  for (int k = 0; k < KG; k++) acc += sp[ids[k] * Wd + t];
  dst[(size_t)row * Wd + t] = acc / 100.0f;
}

// ---------- out = lrelu(in0@W[0] + in1@W[1] + in2@W[2] + b) ----------
__global__ void proj3_kernel(const float* __restrict__ in0, const float* __restrict__ in1,
                             const float* __restrict__ in2, const void* __restrict__ Wt_,
                             const void* __restrict__ bt_, float* __restrict__ out, int C,
                             long Woff, long boff, const int* __restrict__ flag) {
  __shared__ float s0[8 * 128], s1[8 * 128], s2[8 * 128];
  int t = threadIdx.x;  // 128
  int node0 = blockIdx.x * 8;
  int f32 = *flag;
  int nC = 8 * C;
  for (int idx = t; idx < nC; idx += 128) {
    s0[idx] = in0[(size_t)node0 * C + idx];
    s1[idx] = in1[(size_t)node0 * C + idx];
    s2[idx] = in2[(size_t)node0 * C + idx];
  }
  __syncthreads();
  float acc[8] = {0, 0, 0, 0, 0, 0, 0, 0};
  float bd;
  if (f32) {
    const float* W = (const float*)Wt_ + Woff;
    for (int c = 0; c < C; c++) {
      float w0 = W[c * 128 + t], w1 = W[(C + c) * 128 + t], w2 = W[(2 * C + c) * 128 + t];
      #pragma unroll
      for (int n = 0; n < 8; n++)
        acc[n] += s0[n * C + c] * w0 + s1[n * C + c] * w1 + s2[n * C + c] * w2;
    }
    bd = ((const float*)bt_ + boff)[t];
  } else {
    const bf16* W = (const bf16*)Wt_ + Woff;
    for (int c = 0; c < C; c++) {
      float w0 = b2f(W[c * 128 + t]), w1 = b2f(W[(C + c) * 128 + t]), w2 = b2f(W[(2 * C + c) * 128 + t]);
      #pragma unroll
      for (int n = 0; n < 8; n++)
        acc[n] += s0[n * C + c] * w0 + s1[n * C + c] * w1 + s2[n * C + c] * w2;
    }
    bd = b2f(((const bf16*)bt_ + boff)[t]);
  }
  #pragma unroll
  for (int n = 0; n < 8; n++)
    out[(size_t)(node0 + n) * 128 + t] = lrelu(acc[n] + bd);
}

// ---------- u = in@W[0:C], v = in@W[C:2C] ----------
__global__ void proj_dual_kernel(const float* __restrict__ in, const void* __restrict__ Wt_,
                                 float* __restrict__ u, float* __restrict__ v, int C,
                                 long Woff, const int* __restrict__ flag) {
  __shared__ float s0[8 * 128];
  int t = threadIdx.x; int node0 = blockIdx.x * 8;
  int f32 = *flag;
  for (int idx = t; idx < 8 * C; idx += 128) s0[idx] = in[(size_t)node0 * C + idx];
  __syncthreads();
  float au[8] = {0, 0, 0, 0, 0, 0, 0, 0};
  float av[8] = {0, 0, 0, 0, 0, 0, 0, 0};
  if (f32) {
    const float* W = (const float*)Wt_ + Woff;
    for (int c = 0; c < C; c++) {
      float wa = W[c * 128 + t], wb = W[(C + c) * 128 + t];
      #pragma unroll
      for (int n = 0; n < 8; n++) { float x = s0[n * C + c]; au[n] += x * wa; av[n] += x * wb; }
    }
  } else {
    const bf16* W = (const bf16*)Wt_ + Woff;
    for (int c = 0; c < C; c++) {
      float wa = b2f(W[c * 128 + t]), wb = b2f(W[(C + c) * 128 + t]);
      #pragma unroll
      for (int n = 0; n < 8; n++) { float x = s0[n * C + c]; au[n] += x * wa; av[n] += x * wb; }
    }
  }
  #pragma unroll
  for (int n = 0; n < 8; n++) {
    u[(size_t)(node0 + n) * 128 + t] = au[n];
    v[(size_t)(node0 + n) * 128 + t] = av[n];
  }
}

// ---------- edgeconv1 ----------
__global__ void edge_mlp1_kernel(const float* __restrict__ u, const float* __restrict__ v,
                                 const int* __restrict__ nbrp, const void* __restrict__ W2_,
                                 const void* __restrict__ b1_, const void* __restrict__ b2_,
                                 float* __restrict__ y, const int* __restrict__ flag) {
  __shared__ float tl[8][3][128];
  int t = threadIdx.x; int node0 = blockIdx.x * 8; int g = node0 >> 9;
  int f32 = *flag;
  float b1d;
  if (f32) b1d = ((const float*)b1_)[t]; else b1d = b2f(((const bf16*)b1_)[t]);
  for (int n = 0; n < 8; n++) {
    int row = node0 + n;
    float ui = u[(size_t)row * 128 + t], vi = v[(size_t)row * 128 + t];
    #pragma unroll
    for (int k = 0; k < 3; k++) {
      int j = nbrp[row * 3 + k];
      tl[n][k][t] = lrelu(ui + v[(size_t)(g * Nn + j) * 128 + t] - vi + b1d);
    }
  }
  __syncthreads();
  float acc[8][3];
  #pragma unroll
  for (int n = 0; n < 8; n++)
    #pragma unroll
    for (int k = 0; k < 3; k++) acc[n][k] = 0.0f;
  if (f32) {
    const float* W = (const float*)W2_;
    for (int c = 0; c < 128; c++) {
      float w = W[c * 128 + t];
      #pragma unroll
      for (int n = 0; n < 8; n++)
        #pragma unroll
        for (int k = 0; k < 3; k++) acc[n][k] += tl[n][k][c] * w;
    }
  } else {
    const bf16* W = (const bf16*)W2_;
    for (int c = 0; c < 128; c++) {
      float w = b2f(W[c * 128 + t]);
      #pragma unroll
      for (int n = 0; n < 8; n++)
        #pragma unroll
        for (int k = 0; k < 3; k++) acc[n][k] += tl[n][k][c] * w;
    }
  }
  float b2d;
  if (f32) b2d = ((const float*)b2_)[t]; else b2d = b2f(((const bf16*)b2_)[t]);
  #pragma unroll
  for (int n = 0; n < 8; n++) {
    float m = lrelu(acc[n][0] + b2d);
    m = fmaxf(m, lrelu(acc[n][1] + b2d));
    m = fmaxf(m, lrelu(acc[n][2] + b2d));
    y[(size_t)(node0 + n) * 128 + t] = m;
  }
}

// ---------- edgeconv2/3 ----------
__global__ void edge_max_kernel(const float* __restrict__ u, const float* __restrict__ v,
                                const int* __restrict__ nbrp, const void* __restrict__ bias_,
                                float* __restrict__ y, long boff, const int* __restrict__ flag) {
  int row = blockIdx.x; int g = row >> 9; int t = threadIdx.x;  // 128
  float ui = u[(size_t)row * 128 + t], vi = v[(size_t)row * 128 + t];
  float bd;
  if (*flag) bd = ((const float*)bias_ + boff)[t]; else bd = b2f(((const bf16*)bias_ + boff)[t]);
  float m = -3.4e38f;
  #pragma unroll
  for (int k = 0; k < 3; k++) {
    int j = nbrp[row * 3 + k];
    m = fmaxf(m, lrelu(ui - vi + v[(size_t)(g * Nn + j) * 128 + t] + bd));
  }
  y[(size_t)row * 128 + t] = m;
}

// ---------- chunked Gram matrix: G[gl] = Y[g0+gl] Y[g0+gl]^T ----------
__global__ void gram_kernel(const float* __restrict__ y, float* __restrict__ G, int g0) {
  __shared__ float As[64][17], Bs[64][17];
  int bid = blockIdx.x;
  int gl = bid >> 6; int tt = bid & 63; int ti = tt >> 3; int tj = tt & 7;
  int g = g0 + gl;
  int t = threadIdx.x; int tx = t & 15, ty = t >> 4;
  const float* Yg = y + (size_t)g * Nn * Wd;
  float* Gg = G + (size_t)gl * Nn * Nn;
  float c[4][4];
  #pragma unroll
  for (int p = 0; p < 4; p++)
    #pragma unroll
    for (int q = 0; q < 4; q++) c[p][q] = 0.0f;
  for (int k0 = 0; k0 < 128; k0 += 16) {
    for (int idx = t; idx < 1024; idx += 256) {
      int r = idx >> 4, cc = idx & 15;
      As[r][cc] = Yg[(ti * 64 + r) * 128 + k0 + cc];
      Bs[r][cc] = Yg[(tj * 64 + r) * 128 + k0 + cc];
    }
    __syncthreads();
    for (int kk = 0; kk < 16; kk++) {
      float a[4], bb[4];
      #pragma unroll
      for (int p = 0; p < 4; p++) a[p] = As[ty * 4 + p][kk];
      #pragma unroll
      for (int q = 0; q < 4; q++) bb[q] = Bs[tx * 4 + q][kk];
      #pragma unroll
      for (int p = 0; p < 4; p++)
        #pragma unroll
        for (int q = 0; q < 4; q++) c[p][q] += a[p] * bb[q];
    }
    __syncthreads();
  }
  #pragma unroll
  for (int p = 0; p < 4; p++)
    #pragma unroll
    for (int q = 0; q < 4; q++)
      Gg[(size_t)(ti * 64 + ty * 4 + p) * Nn + tj * 64 + tx * 4 + q] = c[p][q];
}

// ---------- mean+max pool ----------
__global__ void pool_kernel(const float* __restrict__ h, float* __restrict__ z,
                            int meanoff, int maxoff) {
  __shared__ float sm[4][128], sx[4][128];
  int g = blockIdx.x; int t = threadIdx.x;  // 512
  int c = t & 127, q = t >> 7;
  const float* hg = h + (size_t)g * Nn * Wd;
  float s = 0.0f, m = -3.4e38f;
  for (int n = q * 128; n < q * 128 + 128; n++) {
    float vv = hg[n * 128 + c];
    s += vv; m = fmaxf(m, vv);
  }
  sm[q][c] = s; sx[q][c] = m;
  __syncthreads();
  if (q == 0) {
    s = sm[0][c] + sm[1][c] + sm[2][c] + sm[3][c];
    m = fmaxf(fmaxf(sx[0][c], sx[1][c]), fmaxf(sx[2][c], sx[3][c]));
    z[g * DIM2 + meanoff + c] = s / 512.0f;
    z[g * DIM2 + maxoff + c] = m;
  }
}

// ---------- BatchNorm1d (batch stats), in place ----------
__global__ void bn_kernel(float* __restrict__ z, const void* __restrict__ gamma,
                          const void* __restrict__ beta, const int* __restrict__ flag) {
  int c = blockIdx.x * 256 + threadIdx.x;
  if (c >= DIM2) return;
  float s = 0.0f;
  for (int r = 0; r < Bg; r++) s += z[r * DIM2 + c];
  float mu = s / 32.0f;
  float v = 0.0f;
  for (int r = 0; r < Bg; r++) { float d = z[r * DIM2 + c] - mu; v += d * d; }
  float var = v / 32.0f;
  float gm, bt;
  if (*flag) { gm = ((const float*)gamma)[c]; bt = ((const float*)beta)[c]; }
  else       { gm = b2f(((const bf16*)gamma)[c]); bt = b2f(((const bf16*)beta)[c]); }
  float scale = gm / sqrtf(var + 1e-5f);
  for (int r = 0; r < Bg; r++) z[r * DIM2 + c] = (z[r * DIM2 + c] - mu) * scale + bt;
}

// ---------- W transpose: WT[d][k] = W[k][d], 32x32 LDS tiles ----------
__global__ void wtrans_kernel(const void* __restrict__ W_, void* __restrict__ WT_,
                              long Woff, const int* __restrict__ flag) {
  __shared__ float tf[32][33];
  __shared__ unsigned short th[32][33];
  int bx = blockIdx.x % 48, by = blockIdx.x / 48;   // 48x48 tile grid
  int tx = threadIdx.x & 31, ty = threadIdx.x >> 5; // 32 x 8
  if (*flag) {
    const float* W = (const float*)W_ + Woff;
    float* WT = (float*)WT_;
    #pragma unroll
    for (int r = 0; r < 32; r += 8)
      tf[ty + r][tx] = W[(size_t)(by * 32 + ty + r) * DIM2 + bx * 32 + tx];
    __syncthreads();
    #pragma unroll
    for (int r = 0; r < 32; r += 8)
      WT[(size_t)(bx * 32 + ty + r) * DIM2 + by * 32 + tx] = tf[tx][ty + r];
  } else {
    const unsigned short* W = (const unsigned short*)W_ + Woff;
    unsigned short* WT = (unsigned short*)WT_;
    #pragma unroll
    for (int r = 0; r < 32; r += 8)
      th[ty + r][tx] = W[(size_t)(by * 32 + ty + r) * DIM2 + bx * 32 + tx];
    __syncthreads();
    #pragma unroll
    for (int r = 0; r < 32; r += 8)
      WT[(size_t)(bx * 32 + ty + r) * DIM2 + by * 32 + tx] = th[tx][ty + r];
  }
}

// ---------- head linear (round-6 proven structure, WT-indexed W reads) ----------
__global__ void hl_kernel(const float* __restrict__ in, const void* __restrict__ WTt,
                          const void* __restrict__ bt_, float* __restrict__ out,
                          long boff, const int* __restrict__ flag) {
  __shared__ float a[32 * 129];
  int t = threadIdx.x; int dcol = blockIdx.x * 8 + (t >> 5); int r = t & 31;
  int f32 = *flag;
  float acc = 0.0f;
  for (int k0 = 0; k0 < DIM2; k0 += 128) {
    for (int idx = t; idx < 4096; idx += 256) {
      int rr = idx >> 7, kk = idx & 127;
      a[rr * 129 + kk] = in[rr * DIM2 + k0 + kk];
    }
    __syncthreads();
    if (f32) {
      const float* WT = (const float*)WTt;
      for (int kk = 0; kk < 128; kk++)
        acc += a[r * 129 + kk] * WT[(size_t)dcol * DIM2 + k0 + kk];
    } else {
      const bf16* WT = (const bf16*)WTt;
      for (int kk = 0; kk < 128; kk++)
        acc += a[r * 129 + kk] * b2f(WT[(size_t)dcol * DIM2 + k0 + kk]);
    }
    __syncthreads();
  }
  float bd;
  if (f32) bd = ((const float*)bt_ + boff)[dcol]; else bd = b2f(((const bf16*)bt_ + boff)[dcol]);
  out[r * DIM2 + dcol] = lrelu(acc + bd);
}

// ---------- final ----------
__global__ void final_kernel(const float* __restrict__ zin, const void* __restrict__ outW,
                             const void* __restrict__ outb, void* __restrict__ out,
                             const int* __restrict__ flag) {
  __shared__ float red[256];
  int r = blockIdx.x, t = threadIdx.x;
  int f32 = *flag;
  float acc = 0.0f;
  if (f32) {
    const float* W = (const float*)outW;
    for (int c = t; c < DIM2; c += 256) acc += zin[r * DIM2 + c] * W[c];
  } else {
    const bf16* W = (const bf16*)outW;
    for (int c = t; c < DIM2; c += 256) acc += zin[r * DIM2 + c] * b2f(W[c]);
  }
  red[t] = acc; __syncthreads();
  for (int s = 128; s > 0; s >>= 1) { if (t < s) red[t] += red[t + s]; __syncthreads(); }
  if (t == 0) {
    float ob;
    if (f32) ob = ((const float*)outb)[0]; else ob = b2f(((const bf16*)outb)[0]);
    float val = red[0] + ob;
    if (f32) ((float*)out)[r] = val;
    else     ((bf16*)out)[r] = __float2bfloat16(val);
  }
}

extern "C" void kernel_launch(void* const* d_in, const int* in_sizes, int n_in,
                              void* d_out, int out_size, void* d_ws, size_t ws_size,
                              hipStream_t stream) {
  const void* x      = d_in[0];
  const void* tag1_W = d_in[2];
  const void* tag1_b = d_in[3];
  const void* tag_W  = d_in[4];
  const void* tag_b  = d_in[5];
  const void* p1_W1  = d_in[6];
  const void* p1_b1  = d_in[7];
  const void* p1_W2  = d_in[8];
  const void* p1_b2  = d_in[9];
  const void* pf_W   = d_in[10];
  const void* pf_b   = d_in[11];
  const void* bn_g   = d_in[12];
  const void* bn_b   = d_in[13];
  const void* lin_W  = d_in[14];
  const void* lin_b  = d_in[15];
  const void* out_W  = d_in[16];
  const void* out_b  = d_in[17];

  // ---- workspace layout: total 10,485,776 floats ≈ 40 MB ----
  float* ws = (float*)d_ws;
  float* XF   = ws + 0;                 // 98304
  float* M16  = ws + 98304;             // 98304
  float* M26  = ws + 196608;            // 98304
  float* Z    = ws + 294912;            // 49152
  float* ZB   = ws + 344064;            // 49152
  int*   FLAG = (int*)(ws + 409600);    // 16
  int*   NBRP = (int*)(ws + 409616);    // 49152 ints
  int*   NBRG = (int*)(ws + 458768);    // 1,638,400 ints -> ends 2,097,168
  float* S0   = ws + 2097168;           // 4 slots x 2,097,152 floats (8 MB each)
  float* S1   = ws + 4194320;           // S0+S1 contiguous -> 16 MB G region
  float* S2   = ws + 6291472;
  float* S3   = ws + 8388624;           // ends 10,485,776 floats
  void*  WT   = (void*)S2;              // head W transpose (S2+S3 dead during head)

  detect_kernel<<<1, 64, 0, stream>>>((const unsigned short*)x, FLAG);
  convert_kernel<<<384, 256, 0, stream>>>(x, XF, Bg * Nn * Fdim, FLAG);
  knn100_kernel<<<Bg * Nn / 4, 256, 0, stream>>>(XF, NBRG);
  knn3_x_kernel<<<Bg * Nn / 16, 256, 0, stream>>>(XF, NBRP);

  // ---- TAG branch: Hb=S0, M1=S1, M2=S2, HN=S3 ----
  gm6_kernel<<<Bg, 512, 0, stream>>>(XF, NBRG, M16);
  gm6_kernel<<<Bg, 512, 0, stream>>>(M16, NBRG, M26);
  proj3_kernel<<<2048, 128, 0, stream>>>(XF, M16, M26, tag1_W, tag1_b, S0, 6, 0, 0, FLAG);
  pool_kernel<<<Bg, 512, 0, stream>>>(S0, Z, 0, 128);

  gm128_kernel<<<Bg * Nn, 128, 0, stream>>>(S0, NBRG, S1);
  gm128_kernel<<<Bg * Nn, 128, 0, stream>>>(S1, NBRG, S2);
  proj3_kernel<<<2048, 128, 0, stream>>>(S0, S1, S2, tag_W, tag_b, S3, 128, 0, 0, FLAG);
  pool_kernel<<<Bg, 512, 0, stream>>>(S3, Z, 256, 384);

  gm128_kernel<<<Bg * Nn, 128, 0, stream>>>(S3, NBRG, S1);
  gm128_kernel<<<Bg * Nn, 128, 0, stream>>>(S1, NBRG, S2);
  proj3_kernel<<<2048, 128, 0, stream>>>(S3, S1, S2, tag_W, tag_b, S0, 128,
                                         3L * 128 * 128, 128, FLAG);
  pool_kernel<<<Bg, 512, 0, stream>>>(S0, Z, 512, 640);

  // ---- point branch: U=S0, V=S1; Y rotates S2/S3; G uses S0+S1 (16 MB) ----
  proj_dual_kernel<<<2048, 128, 0, stream>>>(XF, p1_W1, S0, S1, 6, 0, FLAG);
  edge_mlp1_kernel<<<2048, 128, 0, stream>>>(S0, S1, NBRP, p1_W2, p1_b1, p1_b2, S2, FLAG);  // Y0=S2
  pool_kernel<<<Bg, 512, 0, stream>>>(S2, Z, 768, 1152);

  for (int c = 0; c < Bg; c += GC16) {             // G=S0+S1 (U,V dead)
    gram_kernel<<<GC16 * 64, 256, 0, stream>>>(S2, S0, c);
    knn3_gram_kernel<<<GC16 * Nn / 16, 256, 0, stream>>>(S0, NBRP, c);
  }
  proj_dual_kernel<<<2048, 128, 0, stream>>>(S2, pf_W, S0, S1, 128, 0, FLAG);  // G dead
  edge_max_kernel<<<Bg * Nn, 128, 0, stream>>>(S0, S1, NBRP, pf_b, S3, 0, FLAG);  // Y1=S3
  pool_kernel<<<Bg, 512, 0, stream>>>(S3, Z, 896, 1280);

  for (int c = 0; c < Bg; c += GC16) {             // G=S0+S1 (U,V dead)
    gram_kernel<<<GC16 * 64, 256, 0, stream>>>(S3, S0, c);
    knn3_gram_kernel<<<GC16 * Nn / 16, 256, 0, stream>>>(S0, NBRP, c);
  }
  proj_dual_kernel<<<2048, 128, 0, stream>>>(S3, pf_W, S0, S1, 128, 256L * 128, FLAG);  // G dead
  edge_max_kernel<<<Bg * Nn, 128, 0, stream>>>(S0, S1, NBRP, pf_b, S2, 128, FLAG);  // Y2=S2 (Y0 dead)
  pool_kernel<<<Bg, 512, 0, stream>>>(S2, Z, 1024, 1408);

  // ---- head: per layer, transpose W into WT (S2+S3, dead) then round-6 hl ----
  bn_kernel<<<6, 256, 0, stream>>>(Z, bn_g, bn_b, FLAG);
  wtrans_kernel<<<2304, 256, 0, stream>>>(lin_W, WT, 0L * DIM2 * DIM2, FLAG);
  hl_kernel<<<192, 256, 0, stream>>>(Z, WT, lin_b, ZB, 0L * DIM2, FLAG);
  wtrans_kernel<<<2304, 256, 0, stream>>>(lin_W, WT, 1L * DIM2 * DIM2, FLAG);
  hl_kernel<<<192, 256, 0, stream>>>(ZB, WT, lin_b, Z, 1L * DIM2, FLAG);
  wtrans_kernel<<<2304, 256, 0, stream>>>(lin_W, WT, 2L * DIM2 * DIM2, FLAG);
  hl_kernel<<<192, 256, 0, stream>>>(Z, WT, lin_b, ZB, 2L * DIM2, FLAG);
  wtrans_kernel<<<2304, 256, 0, stream>>>(lin_W, WT, 3L * DIM2 * DIM2, FLAG);
  hl_kernel<<<192, 256, 0, stream>>>(ZB, WT, lin_b, Z, 3L * DIM2, FLAG);
  wtrans_kernel<<<2304, 256, 0, stream>>>(lin_W, WT, 4L * DIM2 * DIM2, FLAG);
  hl_kernel<<<192, 256, 0, stream>>>(Z, WT, lin_b, ZB, 4L * DIM2, FLAG);
  final_kernel<<<Bg, 256, 0, stream>>>(ZB, out_W, out_b, d_out, FLAG);
}

// Round 9
// 1102.906 us; speedup vs baseline: 1.9228x; 1.1925x over previous
//
#include <hip/hip_runtime.h>
#include <hip/hip_bf16.h>

#define Bg 32
#define Nn 512
#define Fdim 6
#define Wd 128
#define KG 100
#define KP 3
#define DIM2 1536
#define GC16 16

typedef __hip_bfloat16 bf16;
typedef unsigned long long ull;

__device__ __forceinline__ float b2f(bf16 v) { return __bfloat162float(v); }
__device__ __forceinline__ float lrelu(float v) { return v > 0.0f ? v : 0.01f * v; }

// ---------- dtype detection (f32=1 / bf16=0), from low-half u16 bit patterns ----------
__global__ void detect_kernel(const unsigned short* __restrict__ x, int* __restrict__ flag) {
  if (threadIdx.x == 0 && blockIdx.x == 0) {
    int big = 0;
    for (int i = 0; i < 512; i += 2) {
      unsigned short u = x[i];
      int e = (u >> 7) & 0xFF;
      if (e >= 140) big++;
    }
    *flag = (big > 20) ? 1 : 0;
  }
}

// ---------- convert x -> f32 ----------
__global__ void convert_kernel(const void* __restrict__ x, float* __restrict__ xf, int n,
                               const int* __restrict__ flag) {
  int i = blockIdx.x * 256 + threadIdx.x;
  if (i >= n) return;
  if (*flag) xf[i] = ((const float*)x)[i];
  else       xf[i] = b2f(((const bf16*)x)[i]);
}

// ---------- branchless sorted-3 insert (k0<=k1<=k2 kept smallest) ----------
__device__ __forceinline__ void ins3b(ull key, ull& k0, ull& k1, ull& k2) {
  ull M0 = k0 < key ? key : k0;  k0 = k0 < key ? k0 : key;
  ull M1 = k1 < M0 ? M0 : k1;    k1 = k1 < M0 ? k1 : M0;
  k2 = k2 < M1 ? k2 : M1;
}

// ---------- kNN k=100: one wave/row; ballot-popcount radix search ----------
__global__ void knn100_kernel(const float* __restrict__ xf, int* __restrict__ nbr) {
  __shared__ float xg[Nn * 7];
  __shared__ float sqv[Nn];
  int t = threadIdx.x; int w = t >> 6; int l = t & 63;
  int row0 = blockIdx.x * 4; int g = row0 >> 9;
  const float* xp = xf + g * (Nn * Fdim);
  for (int j = t; j < Nn; j += 256) {
    float s = 0.0f;
    #pragma unroll
    for (int c = 0; c < Fdim; c++) { float v = xp[j * Fdim + c]; xg[j * 7 + c] = v; s += v * v; }
    sqv[j] = s;
  }
  __syncthreads();
  int i = (row0 & 511) + w;
  float xi[Fdim];
  #pragma unroll
  for (int c = 0; c < Fdim; c++) xi[c] = xg[i * 7 + c];
  float sqi = sqv[i];
  unsigned m[8];
  #pragma unroll
  for (int ch = 0; ch < 8; ch++) {
    int j = ch * 64 + l;
    float dot = 0.0f;
    #pragma unroll
    for (int c = 0; c < Fdim; c++) dot += xi[c] * xg[j * 7 + c];
    float d = sqi + sqv[j] - 2.0f * dot;
    if (j == i) d += 1e10f;
    unsigned u = __float_as_uint(d);
    m[ch] = (u & 0x80000000u) ? ~u : (u | 0x80000000u);
  }
  unsigned T = 0u;
  for (int b = 31; b >= 0; b--) {
    unsigned mid = T | (1u << b);
    int c = 0;
    #pragma unroll
    for (int ch = 0; ch < 8; ch++) c += __popcll(__ballot(m[ch] < mid));
    if (c < KG) T = mid;
  }
  int* outp = nbr + ((size_t)(g * Nn + i)) * KG;
  ull lmask = (1ull << l) - 1ull;
  int base = 0;
  #pragma unroll
  for (int ch = 0; ch < 8; ch++) {
    bool less = m[ch] < T;
    ull bal = __ballot(less);
    if (less) outp[base + __popcll(bal & lmask)] = ch * 64 + l;
    base += __popcll(bal);
  }
  int need = KG - base;
  int eqb = 0;
  #pragma unroll
  for (int ch = 0; ch < 8; ch++) {
    bool eq = (m[ch] == T);
    ull bal = __ballot(eq);
    int gr = eqb + __popcll(bal & lmask);
    if (eq && gr < need) outp[base + gr] = ch * 64 + l;
    eqb += __popcll(bal);
  }
}

// ---------- kNN k=3 on coords: 16 lanes/row ----------
__global__ void knn3_x_kernel(const float* __restrict__ xf, int* __restrict__ nbr) {
  __shared__ float xg[Nn * 7];
  __shared__ float sqv[Nn];
  int t = threadIdx.x; int bid = blockIdx.x;
  int g = bid >> 5;
  const float* xp = xf + g * (Nn * Fdim);
  for (int j = t; j < Nn; j += 256) {
    float s = 0.0f;
    #pragma unroll
    for (int c = 0; c < Fdim; c++) { float v = xp[j * Fdim + c]; xg[j * 7 + c] = v; s += v * v; }
    sqv[j] = s;
  }
  __syncthreads();
  int lr = t >> 4; int sub = t & 15; int l = t & 63;
  int i = ((bid & 31) << 4) + lr;
  float xi[Fdim];
  #pragma unroll
  for (int c = 0; c < Fdim; c++) xi[c] = xg[i * 7 + c];
  float sqi = sqv[i];
  ull k0 = ~0ull, k1 = ~0ull, k2 = ~0ull;
  for (int jj = 0; jj < 32; jj++) {
    int s = (jj + l) & 31;
    int j = sub * 32 + s;
    float dot = 0.0f;
    #pragma unroll
    for (int c = 0; c < Fdim; c++) dot += xi[c] * xg[j * 7 + c];
    float d = sqi + sqv[j] - 2.0f * dot;
    if (j == i) d += 1e10f;
    unsigned u = __float_as_uint(d);
    unsigned m = (u & 0x80000000u) ? ~u : (u | 0x80000000u);
    ins3b(((ull)m << 32) | (unsigned)j, k0, k1, k2);
  }
  #pragma unroll
  for (int off = 1; off <= 8; off <<= 1) {
    ull b0 = __shfl_xor(k0, off, 64);
    ull b1 = __shfl_xor(k1, off, 64);
    ull b2 = __shfl_xor(k2, off, 64);
    ins3b(b0, k0, k1, k2); ins3b(b1, k0, k1, k2); ins3b(b2, k0, k1, k2);
  }
  if (sub == 0) {
    int row = g * Nn + i;
    nbr[row * 3 + 0] = (int)(k0 & 0xFFFFFFFFu);
    nbr[row * 3 + 1] = (int)(k1 & 0xFFFFFFFFu);
    nbr[row * 3 + 2] = (int)(k2 & 0xFFFFFFFFu);
  }
}

// ---------- kNN k=3 from chunked Gram ----------
__global__ void knn3_gram_kernel(const float* __restrict__ G, int* __restrict__ nbr, int g0) {
  __shared__ float sqv[Nn];
  int t = threadIdx.x; int bid = blockIdx.x;
  int gl = bid >> 5; int g = g0 + gl;
  const float* Gg = G + (size_t)gl * Nn * Nn;
  for (int j = t; j < Nn; j += 256) sqv[j] = Gg[(size_t)j * Nn + j];
  __syncthreads();
  int lr = t >> 4; int sub = t & 15; int l = t & 63;
  int i = ((bid & 31) << 4) + lr;
  float sqi = sqv[i];
  const float* Gr = Gg + (size_t)i * Nn;
  ull k0 = ~0ull, k1 = ~0ull, k2 = ~0ull;
  for (int jj = 0; jj < 32; jj++) {
    int s = (jj + l) & 31;
    int j = sub * 32 + s;
    float d = sqi + sqv[j] - 2.0f * Gr[j];
    if (j == i) d += 1e10f;
    unsigned u = __float_as_uint(d);
    unsigned m = (u & 0x80000000u) ? ~u : (u | 0x80000000u);
    ins3b(((ull)m << 32) | (unsigned)j, k0, k1, k2);
  }
  #pragma unroll
  for (int off = 1; off <= 8; off <<= 1) {
    ull b0 = __shfl_xor(k0, off, 64);
    ull b1 = __shfl_xor(k1, off, 64);
    ull b2 = __shfl_xor(k2, off, 64);
    ins3b(b0, k0, k1, k2); ins3b(b1, k0, k1, k2); ins3b(b2, k0, k1, k2);
  }
  if (sub == 0) {
    int row = g * Nn + i;
    nbr[row * 3 + 0] = (int)(k0 & 0xFFFFFFFFu);
    nbr[row * 3 + 1] = (int)(k1 & 0xFFFFFFFFu);
    nbr[row * 3 + 2] = (int)(k2 & 0xFFFFFFFFu);
  }
}

// ---------- neighbor-mean over 100, C=6 ----------
__global__ void gm6_kernel(const float* __restrict__ src, const int* __restrict__ nbr,
                           float* __restrict__ dst) {
  __shared__ float s[Nn * Fdim];
  int g = blockIdx.x; int t = threadIdx.x;  // 512
  const float* sp = src + g * (Nn * Fdim);
  for (int idx = t; idx < Nn * Fdim; idx += 512) s[idx] = sp[idx];
  __syncthreads();
  float acc[Fdim] = {0, 0, 0, 0, 0, 0};
  const int* nb = nbr + ((size_t)(g * Nn + t)) * KG;
  for (int k = 0; k < KG; k++) {
    int j = nb[k];
    #pragma unroll
    for (int c = 0; c < Fdim; c++) acc[c] += s[j * Fdim + c];
  }
  float* dp = dst + (size_t)(g * Nn + t) * Fdim;
  #pragma unroll
  for (int c = 0; c < Fdim; c++) dp[c] = acc[c] / 100.0f;
}

// ---------- neighbor-mean over 100, C=128 ----------
__global__ void gm128_kernel(const float* __restrict__ src, const int* __restrict__ nbr,
                             float* __restrict__ dst) {
  __shared__ int ids[KG];
  int row = blockIdx.x; int g = row >> 9; int t = threadIdx.x;  // 128
  if (t < KG) ids[t] = nbr[(size_t)row * KG + t];
  __syncthreads();
  const float* sp = src + (size_t)g * Nn * Wd;
  float acc = 0.0f;
  #pragma unroll 4
  for (int k = 0; k < KG; k++) acc += sp[ids[k] * Wd + t];
  dst[(size_t)row * Wd + t] = acc / 100.0f;
}

// ---------- out = lrelu(in0@W[0]+in1@W[1]+in2@W[2]+b); uniform global act reads ----------
__global__ void proj3_kernel(const float* __restrict__ in0, const float* __restrict__ in1,
                             const float* __restrict__ in2, const void* __restrict__ Wt_,
                             const void* __restrict__ bt_, float* __restrict__ out, int C,
                             long Woff, long boff, const int* __restrict__ flag) {
  int t = threadIdx.x;  // 128
  int node0 = blockIdx.x * 8;
  int f32 = *flag;
  float acc[8] = {0, 0, 0, 0, 0, 0, 0, 0};
  const float* p0 = in0 + (size_t)node0 * C;
  const float* p1 = in1 + (size_t)node0 * C;
  const float* p2 = in2 + (size_t)node0 * C;
  float bd;
  if (C == 128) {
    if (f32) {
      const float* W = (const float*)Wt_ + Woff;
      for (int c0 = 0; c0 < 128; c0 += 8) {
        float w0[8], w1[8], w2[8];
        #pragma unroll
        for (int q = 0; q < 8; q++) {
          w0[q] = W[(c0 + q) * 128 + t];
          w1[q] = W[(128 + c0 + q) * 128 + t];
          w2[q] = W[(256 + c0 + q) * 128 + t];
        }
        #pragma unroll
        for (int n = 0; n < 8; n++) {
          float a = acc[n];
          #pragma unroll
          for (int q = 0; q < 8; q++) {
            a += p0[n * 128 + c0 + q] * w0[q];
            a += p1[n * 128 + c0 + q] * w1[q];
            a += p2[n * 128 + c0 + q] * w2[q];
          }
          acc[n] = a;
        }
      }
      bd = ((const float*)bt_ + boff)[t];
    } else {
      const bf16* W = (const bf16*)Wt_ + Woff;
      for (int c0 = 0; c0 < 128; c0 += 8) {
        float w0[8], w1[8], w2[8];
        #pragma unroll
        for (int q = 0; q < 8; q++) {
          w0[q] = b2f(W[(c0 + q) * 128 + t]);
          w1[q] = b2f(W[(128 + c0 + q) * 128 + t]);
          w2[q] = b2f(W[(256 + c0 + q) * 128 + t]);
        }
        #pragma unroll
        for (int n = 0; n < 8; n++) {
          float a = acc[n];
          #pragma unroll
          for (int q = 0; q < 8; q++) {
            a += p0[n * 128 + c0 + q] * w0[q];
            a += p1[n * 128 + c0 + q] * w1[q];
            a += p2[n * 128 + c0 + q] * w2[q];
          }
          acc[n] = a;
        }
      }
      bd = b2f(((const bf16*)bt_ + boff)[t]);
    }
  } else {  // C == 6
    if (f32) {
      const float* W = (const float*)Wt_ + Woff;
      for (int c = 0; c < 6; c++) {
        float w0 = W[c * 128 + t], w1 = W[(6 + c) * 128 + t], w2 = W[(12 + c) * 128 + t];
        #pragma unroll
        for (int n = 0; n < 8; n++)
          acc[n] += p0[n * 6 + c] * w0 + p1[n * 6 + c] * w1 + p2[n * 6 + c] * w2;
      }
      bd = ((const float*)bt_ + boff)[t];
    } else {
      const bf16* W = (const bf16*)Wt_ + Woff;
      for (int c = 0; c < 6; c++) {
        float w0 = b2f(W[c * 128 + t]), w1 = b2f(W[(6 + c) * 128 + t]), w2 = b2f(W[(12 + c) * 128 + t]);
        #pragma unroll
        for (int n = 0; n < 8; n++)
          acc[n] += p0[n * 6 + c] * w0 + p1[n * 6 + c] * w1 + p2[n * 6 + c] * w2;
      }
      bd = b2f(((const bf16*)bt_ + boff)[t]);
    }
  }
  #pragma unroll
  for (int n = 0; n < 8; n++)
    out[(size_t)(node0 + n) * 128 + t] = lrelu(acc[n] + bd);
}

// ---------- u = in@W[0:C], v = in@W[C:2C]; uniform global act reads ----------
__global__ void proj_dual_kernel(const float* __restrict__ in, const void* __restrict__ Wt_,
                                 float* __restrict__ u, float* __restrict__ v, int C,
                                 long Woff, const int* __restrict__ flag) {
  int t = threadIdx.x; int node0 = blockIdx.x * 8;
  int f32 = *flag;
  float au[8] = {0, 0, 0, 0, 0, 0, 0, 0};
  float av[8] = {0, 0, 0, 0, 0, 0, 0, 0};
  const float* p = in + (size_t)node0 * C;
  if (C == 128) {
    if (f32) {
      const float* W = (const float*)Wt_ + Woff;
      for (int c0 = 0; c0 < 128; c0 += 8) {
        float wa[8], wb[8];
        #pragma unroll
        for (int q = 0; q < 8; q++) {
          wa[q] = W[(c0 + q) * 128 + t];
          wb[q] = W[(128 + c0 + q) * 128 + t];
        }
        #pragma unroll
        for (int n = 0; n < 8; n++) {
          float a = au[n], b = av[n];
          #pragma unroll
          for (int q = 0; q < 8; q++) {
            float x = p[n * 128 + c0 + q];
            a += x * wa[q]; b += x * wb[q];
          }
          au[n] = a; av[n] = b;
        }
      }
    } else {
      const bf16* W = (const bf16*)Wt_ + Woff;
      for (int c0 = 0; c0 < 128; c0 += 8) {
        float wa[8], wb[8];
        #pragma unroll
        for (int q = 0; q < 8; q++) {
          wa[q] = b2f(W[(c0 + q) * 128 + t]);
          wb[q] = b2f(W[(128 + c0 + q) * 128 + t]);
        }
        #pragma unroll
        for (int n = 0; n < 8; n++) {
          float a = au[n], b = av[n];
          #pragma unroll
          for (int q = 0; q < 8; q++) {
            float x = p[n * 128 + c0 + q];
            a += x * wa[q]; b += x * wb[q];
          }
          au[n] = a; av[n] = b;
        }
      }
    }
  } else {  // C == 6
    if (f32) {
      const float* W = (const float*)Wt_ + Woff;
      for (int c = 0; c < 6; c++) {
        float wa = W[c * 128 + t], wb = W[(6 + c) * 128 + t];
        #pragma unroll
        for (int n = 0; n < 8; n++) { float x = p[n * 6 + c]; au[n] += x * wa; av[n] += x * wb; }
      }
    } else {
      const bf16* W = (const bf16*)Wt_ + Woff;
      for (int c = 0; c < 6; c++) {
        float wa = b2f(W[c * 128 + t]), wb = b2f(W[(6 + c) * 128 + t]);
        #pragma unroll
        for (int n = 0; n < 8; n++) { float x = p[n * 6 + c]; au[n] += x * wa; av[n] += x * wb; }
      }
    }
  }
  #pragma unroll
  for (int n = 0; n < 8; n++) {
    u[(size_t)(node0 + n) * 128 + t] = au[n];
    v[(size_t)(node0 + n) * 128 + t] = av[n];
  }
}

// ---------- edgeconv1: float4 tl reads + batched weight loads ----------
__global__ void edge_mlp1_kernel(const float* __restrict__ u, const float* __restrict__ v,
                                 const int* __restrict__ nbrp, const void* __restrict__ W2_,
                                 const void* __restrict__ b1_, const void* __restrict__ b2_,
                                 float* __restrict__ y, const int* __restrict__ flag) {
  __shared__ float tl[8][3][128];
  int t = threadIdx.x; int node0 = blockIdx.x * 8; int g = node0 >> 9;
  int f32 = *flag;
  float b1d;
  if (f32) b1d = ((const float*)b1_)[t]; else b1d = b2f(((const bf16*)b1_)[t]);
  for (int n = 0; n < 8; n++) {
    int row = node0 + n;
    float ui = u[(size_t)row * 128 + t], vi = v[(size_t)row * 128 + t];
    #pragma unroll
    for (int k = 0; k < 3; k++) {
      int j = nbrp[row * 3 + k];
      tl[n][k][t] = lrelu(ui + v[(size_t)(g * Nn + j) * 128 + t] - vi + b1d);
    }
  }
  __syncthreads();
  float acc[8][3];
  #pragma unroll
  for (int n = 0; n < 8; n++)
    #pragma unroll
    for (int k = 0; k < 3; k++) acc[n][k] = 0.0f;
  if (f32) {
    const float* W = (const float*)W2_;
    for (int c0 = 0; c0 < 128; c0 += 4) {
      float wv[4];
      #pragma unroll
      for (int q = 0; q < 4; q++) wv[q] = W[(c0 + q) * 128 + t];
      #pragma unroll
      for (int n = 0; n < 8; n++)
        #pragma unroll
        for (int k = 0; k < 3; k++) {
          float4 tv = *(const float4*)&tl[n][k][c0];
          acc[n][k] += tv.x * wv[0] + tv.y * wv[1] + tv.z * wv[2] + tv.w * wv[3];
        }
    }
  } else {
    const bf16* W = (const bf16*)W2_;
    for (int c0 = 0; c0 < 128; c0 += 4) {
      float wv[4];
      #pragma unroll
      for (int q = 0; q < 4; q++) wv[q] = b2f(W[(c0 + q) * 128 + t]);
      #pragma unroll
      for (int n = 0; n < 8; n++)
        #pragma unroll
        for (int k = 0; k < 3; k++) {
          float4 tv = *(const float4*)&tl[n][k][c0];
          acc[n][k] += tv.x * wv[0] + tv.y * wv[1] + tv.z * wv[2] + tv.w * wv[3];
        }
    }
  }
  float b2d;
  if (f32) b2d = ((const float*)b2_)[t]; else b2d = b2f(((const bf16*)b2_)[t]);
  #pragma unroll
  for (int n = 0; n < 8; n++) {
    float m = lrelu(acc[n][0] + b2d);
    m = fmaxf(m, lrelu(acc[n][1] + b2d));
    m = fmaxf(m, lrelu(acc[n][2] + b2d));
    y[(size_t)(node0 + n) * 128 + t] = m;
  }
}

// ---------- edgeconv2/3 ----------
__global__ void edge_max_kernel(const float* __restrict__ u, const float* __restrict__ v,
                                const int* __restrict__ nbrp, const void* __restrict__ bias_,
                                float* __restrict__ y, long boff, const int* __restrict__ flag) {
  int row = blockIdx.x; int g = row >> 9; int t = threadIdx.x;  // 128
  float ui = u[(size_t)row * 128 + t], vi = v[(size_t)row * 128 + t];
  float bd;
  if (*flag) bd = ((const float*)bias_ + boff)[t]; else bd = b2f(((const bf16*)bias_ + boff)[t]);
  float m = -3.4e38f;
  #pragma unroll
  for (int k = 0; k < 3; k++) {
    int j = nbrp[row * 3 + k];
    m = fmaxf(m, lrelu(ui - vi + v[(size_t)(g * Nn + j) * 128 + t] + bd));
  }
  y[(size_t)row * 128 + t] = m;
}

// ---------- chunked Gram matrix ----------
__global__ void gram_kernel(const float* __restrict__ y, float* __restrict__ G, int g0) {
  __shared__ float As[64][17], Bs[64][17];
  int bid = blockIdx.x;
  int gl = bid >> 6; int tt = bid & 63; int ti = tt >> 3; int tj = tt & 7;
  int g = g0 + gl;
  int t = threadIdx.x; int tx = t & 15, ty = t >> 4;
  const float* Yg = y + (size_t)g * Nn * Wd;
  float* Gg = G + (size_t)gl * Nn * Nn;
  float c[4][4];
  #pragma unroll
  for (int p = 0; p < 4; p++)
    #pragma unroll
    for (int q = 0; q < 4; q++) c[p][q] = 0.0f;
  for (int k0 = 0; k0 < 128; k0 += 16) {
    for (int idx = t; idx < 1024; idx += 256) {
      int r = idx >> 4, cc = idx & 15;
      As[r][cc] = Yg[(ti * 64 + r) * 128 + k0 + cc];
      Bs[r][cc] = Yg[(tj * 64 + r) * 128 + k0 + cc];
    }
    __syncthreads();
    for (int kk = 0; kk < 16; kk++) {
      float a[4], bb[4];
      #pragma unroll
      for (int p = 0; p < 4; p++) a[p] = As[ty * 4 + p][kk];
      #pragma unroll
      for (int q = 0; q < 4; q++) bb[q] = Bs[tx * 4 + q][kk];
      #pragma unroll
      for (int p = 0; p < 4; p++)
        #pragma unroll
        for (int q = 0; q < 4; q++) c[p][q] += a[p] * bb[q];
    }
    __syncthreads();
  }
  #pragma unroll
  for (int p = 0; p < 4; p++)
    #pragma unroll
    for (int q = 0; q < 4; q++)
      Gg[(size_t)(ti * 64 + ty * 4 + p) * Nn + tj * 64 + tx * 4 + q] = c[p][q];
}

// ---------- two-pass mean+max pool ----------
__global__ void pool1_kernel(const float* __restrict__ h, float* __restrict__ pp) {
  int b = blockIdx.x;                 // 256: g*8 + chunk
  int g = b >> 3, ch = b & 7;
  int t = threadIdx.x;                // 128
  const float* hg = h + (size_t)g * Nn * Wd + (size_t)ch * 64 * Wd;
  float s = 0.0f, m = -3.4e38f;
  #pragma unroll 4
  for (int n = 0; n < 64; n++) {
    float vv = hg[n * 128 + t];
    s += vv; m = fmaxf(m, vv);
  }
  pp[b * 256 + t] = s;
  pp[b * 256 + 128 + t] = m;
}

__global__ void pool2_kernel(const float* __restrict__ pp, float* __restrict__ z,
                             int meanoff, int maxoff) {
  int g = blockIdx.x; int t = threadIdx.x;  // 128
  float s = 0.0f, m = -3.4e38f;
  #pragma unroll
  for (int q = 0; q < 8; q++) {
    s += pp[(g * 8 + q) * 256 + t];
    m = fmaxf(m, pp[(g * 8 + q) * 256 + 128 + t]);
  }
  z[g * DIM2 + meanoff + t] = s / 512.0f;
  z[g * DIM2 + maxoff + t] = m;
}

// ---------- BatchNorm1d (batch stats), in place ----------
__global__ void bn_kernel(float* __restrict__ z, const void* __restrict__ gamma,
                          const void* __restrict__ beta, const int* __restrict__ flag) {
  int c = blockIdx.x * 256 + threadIdx.x;
  if (c >= DIM2) return;
  float s = 0.0f;
  for (int r = 0; r < Bg; r++) s += z[r * DIM2 + c];
  float mu = s / 32.0f;
  float v = 0.0f;
  for (int r = 0; r < Bg; r++) { float d = z[r * DIM2 + c] - mu; v += d * d; }
  float var = v / 32.0f;
  float gm, bt;
  if (*flag) { gm = ((const float*)gamma)[c]; bt = ((const float*)beta)[c]; }
  else       { gm = b2f(((const bf16*)gamma)[c]); bt = b2f(((const bf16*)beta)[c]); }
  float scale = gm / sqrtf(var + 1e-5f);
  for (int r = 0; r < Bg; r++) z[r * DIM2 + c] = (z[r * DIM2 + c] - mu) * scale + bt;
}

// ---------- W transpose: WT[d][k] = W[k][d], 32x32 LDS tiles ----------
__global__ void wtrans_kernel(const void* __restrict__ W_, void* __restrict__ WT_,
                              long Woff, const int* __restrict__ flag) {
  __shared__ float tf[32][33];
  __shared__ unsigned short th[32][33];
  int bx = blockIdx.x % 48, by = blockIdx.x / 48;
  int tx = threadIdx.x & 31, ty = threadIdx.x >> 5; // 32 x 8
  if (*flag) {
    const float* W = (const float*)W_ + Woff;
    float* WT = (float*)WT_;
    #pragma unroll
    for (int r = 0; r < 32; r += 8)
      tf[ty + r][tx] = W[(size_t)(by * 32 + ty + r) * DIM2 + bx * 32 + tx];
    __syncthreads();
    #pragma unroll
    for (int r = 0; r < 32; r += 8)
      WT[(size_t)(bx * 32 + ty + r) * DIM2 + by * 32 + tx] = tf[tx][ty + r];
  } else {
    const unsigned short* W = (const unsigned short*)W_ + Woff;
    unsigned short* WT = (unsigned short*)WT_;
    #pragma unroll
    for (int r = 0; r < 32; r += 8)
      th[ty + r][tx] = W[(size_t)(by * 32 + ty + r) * DIM2 + bx * 32 + tx];
    __syncthreads();
    #pragma unroll
    for (int r = 0; r < 32; r += 8)
      WT[(size_t)(bx * 32 + ty + r) * DIM2 + by * 32 + tx] = th[tx][ty + r];
  }
}

// ---------- head linear: float4 LDS reads + batched WT loads ----------
__global__ void hl_kernel(const float* __restrict__ in, const void* __restrict__ WTt,
                          const void* __restrict__ bt_, float* __restrict__ out,
                          long boff, const int* __restrict__ flag) {
  __shared__ float a[32 * 132];
  int t = threadIdx.x; int dcol = blockIdx.x * 8 + (t >> 5); int r = t & 31;
  int f32 = *flag;
  float acc = 0.0f;
  for (int k0 = 0; k0 < DIM2; k0 += 128) {
    for (int idx = t; idx < 4096; idx += 256) {
      int rr = idx >> 7, kk = idx & 127;
      a[rr * 132 + kk] = in[rr * DIM2 + k0 + kk];
    }
    __syncthreads();
    if (f32) {
      const float* WT = (const float*)WTt;
      for (int kk = 0; kk < 128; kk += 4) {
        float wv[4];
        #pragma unroll
        for (int q = 0; q < 4; q++) wv[q] = WT[(size_t)dcol * DIM2 + k0 + kk + q];
        float4 av = *(const float4*)&a[r * 132 + kk];
        acc += av.x * wv[0] + av.y * wv[1] + av.z * wv[2] + av.w * wv[3];
      }
    } else {
      const bf16* WT = (const bf16*)WTt;
      for (int kk = 0; kk < 128; kk += 4) {
        float wv[4];
        #pragma unroll
        for (int q = 0; q < 4; q++) wv[q] = b2f(WT[(size_t)dcol * DIM2 + k0 + kk + q]);
        float4 av = *(const float4*)&a[r * 132 + kk];
        acc += av.x * wv[0] + av.y * wv[1] + av.z * wv[2] + av.w * wv[3];
      }
    }
    __syncthreads();
  }
  float bd;
  if (f32) bd = ((const float*)bt_ + boff)[dcol]; else bd = b2f(((const bf16*)bt_ + boff)[dcol]);
  out[r * DIM2 + dcol] = lrelu(acc + bd);
}

// ---------- final ----------
__global__ void final_kernel(const float* __restrict__ zin, const void* __restrict__ outW,
                             const void* __restrict__ outb, void* __restrict__ out,
                             const int* __restrict__ flag) {
  __shared__ float red[256];
  int r = blockIdx.x, t = threadIdx.x;
  int f32 = *flag;
  float acc = 0.0f;
  if (f32) {
    const float* W = (const float*)outW;
    for (int c = t; c < DIM2; c += 256) acc += zin[r * DIM2 + c] * W[c];
  } else {
    const bf16* W = (const bf16*)outW;
    for (int c = t; c < DIM2; c += 256) acc += zin[r * DIM2 + c] * b2f(W[c]);
  }
  red[t] = acc; __syncthreads();
  for (int s = 128; s > 0; s >>= 1) { if (t < s) red[t] += red[t + s]; __syncthreads(); }
  if (t == 0) {
    float ob;
    if (f32) ob = ((const float*)outb)[0]; else ob = b2f(((const bf16*)outb)[0]);
    float val = red[0] + ob;
    if (f32) ((float*)out)[r] = val;
    else     ((bf16*)out)[r] = __float2bfloat16(val);
  }
}

extern "C" void kernel_launch(void* const* d_in, const int* in_sizes, int n_in,
                              void* d_out, int out_size, void* d_ws, size_t ws_size,
                              hipStream_t stream) {
  const void* x      = d_in[0];
  const void* tag1_W = d_in[2];
  const void* tag1_b = d_in[3];
  const void* tag_W  = d_in[4];
  const void* tag_b  = d_in[5];
  const void* p1_W1  = d_in[6];
  const void* p1_b1  = d_in[7];
  const void* p1_W2  = d_in[8];
  const void* p1_b2  = d_in[9];
  const void* pf_W   = d_in[10];
  const void* pf_b   = d_in[11];
  const void* bn_g   = d_in[12];
  const void* bn_b   = d_in[13];
  const void* lin_W  = d_in[14];
  const void* lin_b  = d_in[15];
  const void* out_W  = d_in[16];
  const void* out_b  = d_in[17];

  // ---- workspace layout: total 10,485,776 floats ≈ 40 MB ----
  float* ws = (float*)d_ws;
  float* XF   = ws + 0;                 // 98304
  float* M16  = ws + 98304;             // 98304 (dead after proj3#1 -> reused as PP)
  float* M26  = ws + 196608;            // 98304
  float* Z    = ws + 294912;            // 49152
  float* ZB   = ws + 344064;            // 49152
  int*   FLAG = (int*)(ws + 409600);    // 16
  int*   NBRP = (int*)(ws + 409616);    // 49152 ints
  int*   NBRG = (int*)(ws + 458768);    // 1,638,400 ints -> ends 2,097,168
  float* S0   = ws + 2097168;           // 4 slots x 2,097,152 floats (8 MB each)
  float* S1   = ws + 4194320;           // S0+S1 contiguous -> 16 MB G region
  float* S2   = ws + 6291472;
  float* S3   = ws + 8388624;           // ends 10,485,776 floats
  void*  WT   = (void*)S2;              // head W transpose (S2+S3 dead during head)
  float* PP   = M16;                    // pool partials (65536 floats, M16 dead then)

  detect_kernel<<<1, 64, 0, stream>>>((const unsigned short*)x, FLAG);
  convert_kernel<<<384, 256, 0, stream>>>(x, XF, Bg * Nn * Fdim, FLAG);
  knn100_kernel<<<Bg * Nn / 4, 256, 0, stream>>>(XF, NBRG);
  knn3_x_kernel<<<Bg * Nn / 16, 256, 0, stream>>>(XF, NBRP);

  // ---- TAG branch ----
  gm6_kernel<<<Bg, 512, 0, stream>>>(XF, NBRG, M16);
  gm6_kernel<<<Bg, 512, 0, stream>>>(M16, NBRG, M26);
  proj3_kernel<<<2048, 128, 0, stream>>>(XF, M16, M26, tag1_W, tag1_b, S0, 6, 0, 0, FLAG);
  pool1_kernel<<<256, 128, 0, stream>>>(S0, PP);
  pool2_kernel<<<Bg, 128, 0, stream>>>(PP, Z, 0, 128);

  gm128_kernel<<<Bg * Nn, 128, 0, stream>>>(S0, NBRG, S1);
  gm128_kernel<<<Bg * Nn, 128, 0, stream>>>(S1, NBRG, S2);
  proj3_kernel<<<2048, 128, 0, stream>>>(S0, S1, S2, tag_W, tag_b, S3, 128, 0, 0, FLAG);
  pool1_kernel<<<256, 128, 0, stream>>>(S3, PP);
  pool2_kernel<<<Bg, 128, 0, stream>>>(PP, Z, 256, 384);

  gm128_kernel<<<Bg * Nn, 128, 0, stream>>>(S3, NBRG, S1);
  gm128_kernel<<<Bg * Nn, 128, 0, stream>>>(S1, NBRG, S2);
  proj3_kernel<<<2048, 128, 0, stream>>>(S3, S1, S2, tag_W, tag_b, S0, 128,
                                         3L * 128 * 128, 128, FLAG);
  pool1_kernel<<<256, 128, 0, stream>>>(S0, PP);
  pool2_kernel<<<Bg, 128, 0, stream>>>(PP, Z, 512, 640);

  // ---- point branch ----
  proj_dual_kernel<<<2048, 128, 0, stream>>>(XF, p1_W1, S0, S1, 6, 0, FLAG);
  edge_mlp1_kernel<<<2048, 128, 0, stream>>>(S0, S1, NBRP, p1_W2, p1_b1, p1_b2, S2, FLAG);  // Y0=S2
  pool1_kernel<<<256, 128, 0, stream>>>(S2, PP);
  pool2_kernel<<<Bg, 128, 0, stream>>>(PP, Z, 768, 1152);

  for (int c = 0; c < Bg; c += GC16) {             // G=S0+S1 (U,V dead)
    gram_kernel<<<GC16 * 64, 256, 0, stream>>>(S2, S0, c);
    knn3_gram_kernel<<<GC16 * Nn / 16, 256, 0, stream>>>(S0, NBRP, c);
  }
  proj_dual_kernel<<<2048, 128, 0, stream>>>(S2, pf_W, S0, S1, 128, 0, FLAG);  // G dead
  edge_max_kernel<<<Bg * Nn, 128, 0, stream>>>(S0, S1, NBRP, pf_b, S3, 0, FLAG);  // Y1=S3
  pool1_kernel<<<256, 128, 0, stream>>>(S3, PP);
  pool2_kernel<<<Bg, 128, 0, stream>>>(PP, Z, 896, 1280);

  for (int c = 0; c < Bg; c += GC16) {             // G=S0+S1 (U,V dead)
    gram_kernel<<<GC16 * 64, 256, 0, stream>>>(S3, S0, c);
    knn3_gram_kernel<<<GC16 * Nn / 16, 256, 0, stream>>>(S0, NBRP, c);
  }
  proj_dual_kernel<<<2048, 128, 0, stream>>>(S3, pf_W, S0, S1, 128, 256L * 128, FLAG);  // G dead
  edge_max_kernel<<<Bg * Nn, 128, 0, stream>>>(S0, S1, NBRP, pf_b, S2, 128, FLAG);  // Y2=S2
  pool1_kernel<<<256, 128, 0, stream>>>(S2, PP);
  pool2_kernel<<<Bg, 128, 0, stream>>>(PP, Z, 1024, 1408);

  // ---- head ----
  bn_kernel<<<6, 256, 0, stream>>>(Z, bn_g, bn_b, FLAG);
  wtrans_kernel<<<2304, 256, 0, stream>>>(lin_W, WT, 0L * DIM2 * DIM2, FLAG);
  hl_kernel<<<192, 256, 0, stream>>>(Z, WT, lin_b, ZB, 0L * DIM2, FLAG);
  wtrans_kernel<<<2304, 256, 0, stream>>>(lin_W, WT, 1L * DIM2 * DIM2, FLAG);
  hl_kernel<<<192, 256, 0, stream>>>(ZB, WT, lin_b, Z, 1L * DIM2, FLAG);
  wtrans_kernel<<<2304, 256, 0, stream>>>(lin_W, WT, 2L * DIM2 * DIM2, FLAG);
  hl_kernel<<<192, 256, 0, stream>>>(Z, WT, lin_b, ZB, 2L * DIM2, FLAG);
  wtrans_kernel<<<2304, 256, 0, stream>>>(lin_W, WT, 3L * DIM2 * DIM2, FLAG);
  hl_kernel<<<192, 256, 0, stream>>>(ZB, WT, lin_b, Z, 3L * DIM2, FLAG);
  wtrans_kernel<<<2304, 256, 0, stream>>>(lin_W, WT, 4L * DIM2 * DIM2, FLAG);
  hl_kernel<<<192, 256, 0, stream>>>(Z, WT, lin_b, ZB, 4L * DIM2, FLAG);
  final_kernel<<<Bg, 256, 0, stream>>>(ZB, out_W, out_b, d_out, FLAG);
}